// Round 5
// baseline (1980.915 us; speedup 1.0000x reference)
//
#include <hip/hip_runtime.h>
#include <hip/hip_bf16.h>
#include <hip/hip_fp16.h>
#include <math.h>

typedef __hip_bfloat16 bf16;
typedef __attribute__((ext_vector_type(8))) short short8;
typedef __attribute__((ext_vector_type(4))) float f32x4;
typedef __attribute__((ext_vector_type(8))) _Float16 half8;

#define NATT 11
#define Bb 8
#define Ss 512
#define Dd 768
#define Hh 256
#define WSLICE 589824L  // 768*768

__device__ __forceinline__ void stf(float* p, float v) { *p = v; }
__device__ __forceinline__ void stf(bf16* p, float v) { *p = __float2bfloat16(v); }

__device__ __forceinline__ float blo(unsigned u) { return __uint_as_float(u << 16); }
__device__ __forceinline__ float bhi(unsigned u) { return __uint_as_float(u & 0xffff0000u); }
__device__ __forceinline__ float b2f(unsigned short u) { return __uint_as_float(((unsigned)u) << 16); }

__device__ __forceinline__ float ldg_any(const void* base, long idx, int flag) {
  if (flag) return ((const float*)base)[idx];
  return __bfloat162float(((const bf16*)base)[idx]);
}

__device__ __forceinline__ unsigned packh2(float a, float b) {
  __half2 hh = __floats2half2_rn(a, b);
  return __builtin_bit_cast(unsigned, hh);
}
__device__ __forceinline__ unsigned short f2h(float v) {
  __half h = __float2half(v);
  return __builtin_bit_cast(unsigned short, h);
}

typedef _Float16 f16x2 __attribute__((ext_vector_type(2)));

__device__ __forceinline__ float dot2u(unsigned a, unsigned b, float c) {
#if __has_builtin(__builtin_amdgcn_fdot2)
  return __builtin_amdgcn_fdot2(__builtin_bit_cast(f16x2, a),
                                __builtin_bit_cast(f16x2, b), c, false);
#else
  __half2 ah = __builtin_bit_cast(__half2, a);
  __half2 bh = __builtin_bit_cast(__half2, b);
  float2 af = __half22float2(ah), bf = __half22float2(bh);
  return c + af.x * bf.x + af.y * bf.y;
#endif
}

// barrier that drains ONLY LDS (lgkmcnt) — leaves global prefetches in flight.
__device__ __forceinline__ void lds_barrier() {
  asm volatile("s_waitcnt lgkmcnt(0)\n\ts_barrier" ::: "memory");
}

__device__ __forceinline__ void load_lds16(const void* g, void* l) {
  __builtin_amdgcn_global_load_lds(
      (const __attribute__((address_space(1))) unsigned int*)g,
      (__attribute__((address_space(3))) unsigned int*)l, 16, 0, 0);
}

// ---------- dtype probe ----------
__global__ __launch_bounds__(64) void probe_kernel(
    const unsigned short* __restrict__ sequ, const unsigned* __restrict__ labu,
    int* __restrict__ flags)
{
  int t = threadIdx.x;
  int wild = 0;
#pragma unroll
  for (int i = 0; i < 4; i++) {
    unsigned short v = sequ[t + i * 64];
    int e = (v >> 7) & 0xFF;
    if (e < 90 || e > 160) wild++;
  }
  int nzodd = 0;
#pragma unroll
  for (int i = 0; i < 2; i++) {
    unsigned w = labu[(t + i * 64) * 2 + 1];
    if (w != 0) nzodd++;
  }
  for (int o = 32; o > 0; o >>= 1) {
    wild  += __shfl_down(wild, o);
    nzodd += __shfl_down(nzodd, o);
  }
  if (t == 0) {
    flags[0] = (wild > 32) ? 1 : 0;
    flags[1] = (nzodd == 0) ? 1 : 0;
  }
}

// ---------- seq -> bf16 ----------
__global__ __launch_bounds__(256) void conv_seq_kernel(
    const void* __restrict__ seq, bf16* __restrict__ seqb,
    const int* __restrict__ flags)
{
  int flag = flags[0];
  long row = blockIdx.x;
#pragma unroll
  for (int i = 0; i < 3; i++) {
    long e = row * Dd + threadIdx.x + i * 256;
    seqb[e] = __float2bfloat16(ldg_any(seq, e, flag));
  }
}

// ---------- generic convert to bf16 (Wih) ----------
__global__ __launch_bounds__(256) void convert_kernel(
    const void* __restrict__ src, bf16* __restrict__ dst, long n,
    const int* __restrict__ flags)
{
  int flag = flags[0];
  long i = (long)blockIdx.x * 256 + threadIdx.x;
  if (i < n) dst[i] = __float2bfloat16(ldg_any(src, i, flag));
}

// ---------- cbias[2][768] = bih + (col<512 ? bhh : 0)  (f32) ----------
__global__ __launch_bounds__(256) void cbias_kernel(
    const void* __restrict__ bih, const void* __restrict__ bhh,
    float* __restrict__ cbias, const int* __restrict__ flags)
{
  int flag = flags[0];
  int i = blockIdx.x * 256 + threadIdx.x;  // grid 6 -> 1536
  int c = i & 767;
  float v = ldg_any(bih, i, flag);
  if (c < 512) v += ldg_any(bhh, i, flag);
  cbias[i] = v;
}

// ---------- Qsmall[11][7][768] = relu(emb7 @ Wq + bq); grid (12, 11) ----------
__global__ __launch_bounds__(256) void smalls_kernel(
    const void* __restrict__ emb, const void* __restrict__ Wq,
    const void* __restrict__ bq, float* __restrict__ Qsmall,
    const int* __restrict__ flags)
{
  int flag = flags[0];
  __shared__ float embsh[7 * 768];
  __shared__ float psum[4][7][64];
  int z = blockIdx.y;
  int bx = blockIdx.x;
  int tid = threadIdx.x;
  int sub = tid >> 6, nl = tid & 63;
  for (int i = tid; i < 7 * 768; i += 256) embsh[i] = ldg_any(emb, i, flag);
  __syncthreads();
  int n = bx * 64 + nl;
  long base = (long)z * WSLICE;
  float acc[7] = {};
  int e0 = sub * 192;
  for (int e = e0; e < e0 + 192; e++) {
    float wv = ldg_any(Wq, base + (long)e * Dd + n, flag);
#pragma unroll
    for (int l = 0; l < 7; l++) acc[l] += embsh[l * 768 + e] * wv;
  }
#pragma unroll
  for (int l = 0; l < 7; l++) psum[sub][l][nl] = acc[l];
  __syncthreads();
  if (sub == 0) {
    float bv = ldg_any(bq, z * Dd + n, flag);
#pragma unroll
    for (int l = 0; l < 7; l++) {
      float v = psum[0][l][nl] + psum[1][l][nl] + psum[2][l][nl] + psum[3][l][nl] + bv;
      Qsmall[((long)z * 7 + l) * Dd + n] = fmaxf(v, 0.f);
    }
  }
}

// ---------- emb rows -> outsm[640+l] (bf16) + qmask7 ----------
__global__ __launch_bounds__(256) void emb_copy_kernel(
    const void* __restrict__ emb, bf16* __restrict__ outsm,
    float* __restrict__ qmask7, const int* __restrict__ flags)
{
  int flag = flags[0];
  int l = blockIdx.x;
  int t = threadIdx.x;
  float s = 0.f;
#pragma unroll
  for (int i = 0; i < 3; i++) {
    int e = t + i * 256;
    float v = ldg_any(emb, (long)l * Dd + e, flag);
    outsm[(long)(640 + l) * Dd + e] = __float2bfloat16(v);
    s += v;
  }
  for (int o = 32; o > 0; o >>= 1) s += __shfl_down(s, o);
  __shared__ float red[4];
  if ((t & 63) == 0) red[t >> 6] = s;
  __syncthreads();
  if (t == 0) {
    float tot = red[0] + red[1] + red[2] + red[3];
    qmask7[l] = (tot != 0.f) ? 1.f : 0.f;
  }
}

// ---------- transpose Wk/Wv branch slices to [N][K] bf16 ----------
__global__ __launch_bounds__(256) void transpose2_kernel(
    const void* __restrict__ Wk, const void* __restrict__ Wv,
    bf16* __restrict__ WT, const int* __restrict__ flags)
{
  int flag = flags[0];
  __shared__ float tile[32][33];
  int z = blockIdx.z;
  int m = z >> 1, wsel = z & 1;
  const void* src = wsel ? Wv : Wk;
  long off = (long)m * WSLICE;
  bf16* dst = WT + (long)z * WSLICE;
  int kk0 = blockIdx.y * 32, n0 = blockIdx.x * 32;
  int tx = threadIdx.x & 31, ty = threadIdx.x >> 5;
#pragma unroll
  for (int i = 0; i < 4; i++)
    tile[ty + i * 8][tx] = ldg_any(src, off + (long)(kk0 + ty + i * 8) * Dd + n0 + tx, flag);
  __syncthreads();
#pragma unroll
  for (int i = 0; i < 4; i++)
    dst[(long)(n0 + ty + i * 8) * Dd + kk0 + tx] = __float2bfloat16(tile[tx][ty + i * 8]);
}

// ---------- MFMA GEMM core: C = epi(scale*A@B^T) ----------
// cMode: 0=bf16, 2=fp32, 3=fp16, 5=fp16 transposed via LDS bounce (coalesced).
// cMode 5 REQUIRES As,Bs to be one contiguous 16KB block.
__device__ __forceinline__ void gemm_mfma_core(
    const bf16* __restrict__ Ab, long ldA,
    const bf16* __restrict__ Bbp, long ldB,
    bf16* As, bf16* Bs, int bm, int bn, int K,
    const void* bias, long bOff,
    void* C, long ldC, int cMode,
    float scale, int relu, int fflag)
{
  int tid = threadIdx.x;
  int lane = tid & 63, w = tid >> 6;
  int mo = (w & 1) * 64, no = (w >> 1) * 64;
  int l15 = lane & 15, q4 = lane >> 4;
  int gr = lane >> 2;
  int gs = (lane & 3) * 8;
  const bf16* aS0 = Ab + (long)(bm + w * 16 + gr) * ldA + gs;
  const bf16* aS1 = aS0 + 64 * ldA;
  const bf16* bS0 = Bbp + (long)(bn + w * 16 + gr) * ldB + gs;
  const bf16* bS1 = bS0 + 64 * ldB;
  bf16* aD0 = As + w * 512;
  bf16* aD1 = As + 2048 + w * 512;
  bf16* bD0 = Bs + w * 512;
  bf16* bD1 = Bs + 2048 + w * 512;

  f32x4 acc[4][4];
#pragma unroll
  for (int i = 0; i < 4; i++)
#pragma unroll
    for (int j = 0; j < 4; j++)
#pragma unroll
      for (int r = 0; r < 4; r++) acc[i][j][r] = 0.f;

  for (int k0 = 0; k0 < K; k0 += 32) {
    load_lds16(aS0, aD0);
    load_lds16(aS1, aD1);
    load_lds16(bS0, bD0);
    load_lds16(bS1, bD1);
    aS0 += 32; aS1 += 32; bS0 += 32; bS1 += 32;
    __syncthreads();
    short8 af[4], bfv[4];
#pragma unroll
    for (int i = 0; i < 4; i++)
      af[i] = *(const short8*)(As + (mo + i * 16 + l15) * 32 + q4 * 8);
#pragma unroll
    for (int j = 0; j < 4; j++)
      bfv[j] = *(const short8*)(Bs + (no + j * 16 + l15) * 32 + q4 * 8);
#pragma unroll
    for (int i = 0; i < 4; i++)
#pragma unroll
      for (int j = 0; j < 4; j++)
        acc[i][j] = __builtin_amdgcn_mfma_f32_16x16x32_bf16(af[i], bfv[j], acc[i][j], 0, 0, 0);
    __syncthreads();
  }

  float bsv[4];
#pragma unroll
  for (int j = 0; j < 4; j++) {
    int colg = bn + no + j * 16 + l15;
    bsv[j] = bias ? ldg_any(bias, bOff + colg, fflag) : 0.f;
  }

  if (cMode == 5) {
    unsigned short* tile = (unsigned short*)As;   // [32][136]
    int cl = (no >> 6) * 16 + l15;
#pragma unroll
    for (int j = 0; j < 4; j++) {
      __syncthreads();
#pragma unroll
      for (int i = 0; i < 4; i++) {
#pragma unroll
        for (int r = 0; r < 4; r++) {
          float v = acc[i][j][r] * scale + bsv[j];
          if (relu) v = fmaxf(v, 0.f);
          tile[cl * 136 + mo + i * 16 + q4 * 4 + r] = f2h(v);
        }
      }
      __syncthreads();
#pragma unroll
      for (int uu = 0; uu < 2; uu++) {
        int u = tid + uu * 256;
        int c = u >> 4, mseg = u & 15;
        int colg = bn + (c >> 4) * 64 + j * 16 + (c & 15);
        uint2 v0 = *(const uint2*)(tile + c * 136 + mseg * 8);
        uint2 v1 = *(const uint2*)(tile + c * 136 + mseg * 8 + 4);
        uint4 pk; pk.x = v0.x; pk.y = v0.y; pk.z = v1.x; pk.w = v1.y;
        *(uint4*)((unsigned short*)C + (long)colg * ldC + bm + mseg * 8) = pk;
      }
    }
    return;
  }

#pragma unroll
  for (int i = 0; i < 4; i++) {
#pragma unroll
    for (int j = 0; j < 4; j++) {
      int colg = bn + no + j * 16 + l15;
#pragma unroll
      for (int r = 0; r < 4; r++) {
        int rowg = bm + mo + i * 16 + q4 * 4 + r;
        float v = acc[i][j][r] * scale + bsv[j];
        if (relu) v = fmaxf(v, 0.f);
        long off2 = (long)rowg * ldC + colg;
        if (cMode == 2)      ((float*)C)[off2] = v;
        else if (cMode == 3) ((unsigned short*)C)[off2] = f2h(v);
        else                 ((bf16*)C)[off2] = __float2bfloat16(v);
      }
    }
  }
}

// ---------- K/V projections + seqW, z: 0..21 = m*2+{K,V}; 22,23 = seqW dir ----------
__global__ __launch_bounds__(256, 2) void proj_kernel(
    const bf16* __restrict__ seqb, const bf16* __restrict__ WT,
    const void* __restrict__ bk, const void* __restrict__ bv,
    const bf16* __restrict__ WihB, const float* __restrict__ cbias,
    unsigned short* __restrict__ Kb, unsigned short* __restrict__ Vt,
    bf16* __restrict__ seqW, const int* __restrict__ flags)
{
  __shared__ __align__(16) bf16 smem[8192];   // contiguous As+Bs (cMode 5 needs this)
  bf16* As = smem;
  bf16* Bs = smem + 4096;
  int z = blockIdx.z;
  if (z < 22) {
    int m = z >> 1, wsel = z & 1;
    const bf16* B = WT + (long)z * WSLICE;
    if (wsel == 0) {
      gemm_mfma_core(seqb, Dd, B, Dd, As, Bs, blockIdx.y * 128, blockIdx.x * 128, Dd,
                     bk, (long)m * Dd, Kb + (long)m * 4096 * Dd, Dd, 3, 1.f, 1, flags[0]);
    } else {
      gemm_mfma_core(seqb, Dd, B, Dd, As, Bs, blockIdx.y * 128, blockIdx.x * 128, Dd,
                     bv, (long)m * Dd, Vt + (long)m * Dd * 4096, 4096, 5, 1.f, 1, flags[0]);
    }
  } else {
    int dir = z - 22;
    // bias = bih + bhh(r,z) precomputed in f32 (fflag=1)
    gemm_mfma_core(seqb, Dd, WihB + (long)dir * WSLICE, Dd, As, Bs,
                   blockIdx.y * 128, blockIdx.x * 128, Dd,
                   cbias, (long)dir * Dd, seqW + (long)dir * 4096 * Dd, Dd, 0,
                   1.f, 0, 1);
  }
}

// ---------- PVW = outsm(768 rows incl emb @640) @ Wih^T (fp32), z = dir ----------
__global__ __launch_bounds__(256, 2) void pvw_kernel(
    const bf16* __restrict__ outsm, const bf16* __restrict__ WihB,
    float* __restrict__ PVW, const int* __restrict__ flags)
{
  __shared__ __align__(16) bf16 As[4096];
  __shared__ __align__(16) bf16 Bs[4096];
  int dir = blockIdx.z;
  gemm_mfma_core(outsm, Dd, WihB + (long)dir * WSLICE, Dd, As, Bs,
                 blockIdx.y * 128, blockIdx.x * 128, Dd,
                 nullptr, 0, PVW + (long)dir * 768 * Dd, Dd, 2, 1.f, 0, flags[0]);
}

// ---------- fused scores+softmax+mask+PV per (k,b) ----------
__global__ __launch_bounds__(512, 2) void attn_kernel(
    const unsigned short* __restrict__ Kb, const unsigned short* __restrict__ Vt,
    const float* __restrict__ Qsmall, const float* __restrict__ qmask7,
    bf16* __restrict__ outsm, float scl)
{
  int blk = blockIdx.x;  // k*8+b
  int k = blk >> 3, b = blk & 7;
  int tid = threadIdx.x;
  int lane = tid & 63, w = tid >> 6;
  __shared__ unsigned qs[7][384];
  __shared__ unsigned short ash[7][512];
  __shared__ float wred[8][7];
  __shared__ float gred[7];
  __shared__ float finv[7];
  for (int i = tid; i < 7 * 384; i += 512) {
    int l = i / 384, e2 = i - l * 384;
    const float* qp = Qsmall + ((long)k * 7 + l) * Dd + 2 * e2;
    qs[l][e2] = packh2(qp[0], qp[1]);
  }
  __syncthreads();
  const uint4* Krow = (const uint4*)(Kb + ((long)k * 4096 + b * 512 + tid) * Dd);
  float sc[7] = {};
  for (int e8 = 0; e8 < 96; e8++) {
    uint4 kv = Krow[e8];
#pragma unroll
    for (int l = 0; l < 7; l++) {
      sc[l] = dot2u(qs[l][e8 * 4],     kv.x, sc[l]);
      sc[l] = dot2u(qs[l][e8 * 4 + 1], kv.y, sc[l]);
      sc[l] = dot2u(qs[l][e8 * 4 + 2], kv.z, sc[l]);
      sc[l] = dot2u(qs[l][e8 * 4 + 3], kv.w, sc[l]);
    }
  }
#pragma unroll
  for (int l = 0; l < 7; l++) sc[l] *= scl;
#pragma unroll
  for (int l = 0; l < 7; l++) {
    float v = sc[l];
    for (int o = 32; o > 0; o >>= 1) v = fmaxf(v, __shfl_down(v, o));
    if (lane == 0) wred[w][l] = v;
  }
  __syncthreads();
  if (tid < 7) {
    float m = wred[0][tid];
#pragma unroll
    for (int i = 1; i < 8; i++) m = fmaxf(m, wred[i][tid]);
    gred[tid] = m;
  }
  __syncthreads();
  float ev[7];
#pragma unroll
  for (int l = 0; l < 7; l++) {
    ev[l] = __expf(sc[l] - gred[l]);
    float v = ev[l];
    for (int o = 32; o > 0; o >>= 1) v += __shfl_down(v, o);
    if (lane == 0) wred[w][l] = v;
  }
  __syncthreads();
  if (tid < 7) {
    float s = 0.f;
#pragma unroll
    for (int i = 0; i < 8; i++) s += wred[i][tid];
    finv[tid] = qmask7[tid] / s;
  }
  __syncthreads();
#pragma unroll
  for (int l = 0; l < 7; l++) ash[l][tid] = f2h(ev[l] * finv[l]);
  __syncthreads();
  for (int rep = 0; rep < 2; rep++) {
    int n = tid + rep * 512;
    if (n >= Dd) break;
    const uint4* Vrow = (const uint4*)(Vt + ((long)k * Dd + n) * 4096 + b * 512);
    float acc[7] = {};
    for (int m8 = 0; m8 < 64; m8++) {
      uint4 vv = Vrow[m8];
#pragma unroll
      for (int l = 0; l < 7; l++) {
        const unsigned* ap = (const unsigned*)&ash[l][0];
        acc[l] = dot2u(ap[m8 * 4],     vv.x, acc[l]);
        acc[l] = dot2u(ap[m8 * 4 + 1], vv.y, acc[l]);
        acc[l] = dot2u(ap[m8 * 4 + 2], vv.z, acc[l]);
        acc[l] = dot2u(ap[m8 * 4 + 3], vv.w, acc[l]);
      }
    }
#pragma unroll
    for (int l = 0; l < 7; l++)
      outsm[((long)blk * 7 + l) * Dd + n] = __float2bfloat16(acc[l]);
  }
}

// ---------- GRU v12: 1024-thread block; weights fit the GRANTED budget ----------
// v11 post-mortem: VGPR budget is pinned at 128/wave no matter which
// waves-per-eu attribute is used (SGPR changed -> attribute reached codegen;
// VGPR stayed 128). WRITE_SIZE 36 MB == exactly one scratch store of the
// ~100-reg afr overflow (100x4x512x176); per-step reloads come from L1/L2
// (invisible in FETCH) and are the 7500 cyc/step bottleneck.
// v12: stop fighting the allocator — 1024 threads (16 waves, forced
// 4 waves/SIMD) halves per-thread weight storage to 96 regs:
//   demand = 96 afr + 12 acc + 4 bfr + ~15 working ~= 127 <= 128. No spill.
// Each wave owns 3 M-tiles (48 rows) x 8 K-tiles; 384 MFMA/step total
// (96/SIMD ~= 465 cyc) + gate phase (tid<256) ~= ~650 cyc/step.
__global__ __launch_bounds__(1024) void gru_kernel(
    const bf16* __restrict__ seqW,   // [2][4096][768] bf16, includes bih + bhh(r,z)
    const float* __restrict__ PVW,   // [2][768][768]; rows n*7+l and 640+l(emb)
    const void* __restrict__ labels,
    const void* __restrict__ Whh, const void* __restrict__ bhh,
    float* __restrict__ hbuf, const int* __restrict__ flags)
{
  int flag = flags[0], lflag = flags[1];
  int idx = blockIdx.x;
  int dir = idx / 88, n = idx - dir * 88;
  int b = n & 7;
  int tid = threadIdx.x;
  int lane = tid & 63, w = tid >> 6;          // w in [0,16)
  int l15 = lane & 15, g4 = lane >> 4;

  // A-fragments: wave w owns M-tiles mt = 3w+t (t=0..2), rows mt*16..mt*16+15.
  // Lane holds W[mt*16+l15][32*kt + 8*g4 + j], packed fp16x2.
  half8 afr[3][8];
#pragma unroll
  for (int t = 0; t < 3; t++) {
    int m0 = (3 * w + t) * 16;
    long rb = ((long)dir * Dd + m0 + l15) * (long)Hh + 8 * g4;
#pragma unroll
    for (int kt = 0; kt < 8; kt++) {
      long eb = rb + 32 * kt;
      uint4 u;
      if (flag) {
        const float4* s4 = (const float4*)((const float*)Whh + eb);
        float4 v0 = s4[0], v1 = s4[1];
        u.x = packh2(v0.x, v0.y); u.y = packh2(v0.z, v0.w);
        u.z = packh2(v1.x, v1.y); u.w = packh2(v1.z, v1.w);
      } else {
        uint4 v = *(const uint4*)((const bf16*)Whh + eb);
        u.x = packh2(blo(v.x), bhi(v.x));
        u.y = packh2(blo(v.y), bhi(v.y));
        u.z = packh2(blo(v.z), bhi(v.z));
        u.w = packh2(blo(v.w), bhi(v.w));
      }
      afr[t][kt] = __builtin_bit_cast(half8, u);
    }
  }

  __shared__ float rowsh[7 * 768];
  __shared__ int labsh[512];
  __shared__ __align__(16) float out_lds[768];
  __shared__ __align__(16) _Float16 hsh[256];
  __shared__ __align__(16) unsigned short xring[4 * 768];  // 4-deep x-row ring

  for (int i = tid; i < 7 * 768; i += 1024) {
    int l = i / 768, row = i - l * 768;
    rowsh[i] = PVW[((long)dir * 768 + n * 7 + l) * Dd + row]
             + PVW[((long)dir * 768 + 640 + l) * Dd + row];
  }
  if (tid < 512)
    labsh[tid] = lflag ? (int)((const long long*)labels)[b * 512 + tid]
                       : ((const int*)labels)[b * 512 + tid];
  if (tid < 256) hsh[tid] = (_Float16)0.f;

  int ch = tid & 255;
  float bh2 = 0.f, hprev = 0.f;
  if (tid < 256) bh2 = ldg_any(bhh, dir * Dd + 512 + ch, flag);

  // x-row DMA: row t is 1536 B; wave0 lanes 0-63 cover bytes 0..1023,
  // wave1 lanes 0-31 cover 1024..1535 (LDS dst = uniform base + lane*16).
  const char* swb = (const char*)seqW + ((long)dir * 4096 + b * 512) * (long)(Dd * 2);
  int dma = (w == 0) || (w == 1 && lane < 32);
  // prime ring slots 0..2
  if (dma) {
#pragma unroll
    for (int s = 0; s < 3; s++) {
      int tp = dir ? 511 - s : s;
      load_lds16(swb + (long)tp * 1536 + w * 1024 + lane * 16,
                 (char*)xring + s * 1536 + w * 1024);
    }
  }
  __syncthreads();   // drains vmcnt(0)+lgkmcnt(0): ring 0..2 ready, hsh ready

  for (int tt = 0; tt < Ss; tt++) {
    // issue DMA for step tt+3 (slot (tt+3)&3); clamped row at the tail
    {
      int ttp = (tt + 3 < Ss) ? tt + 3 : Ss - 1;
      int tp = dir ? 511 - ttp : ttp;
      if (dma)
        load_lds16(swb + (long)tp * 1536 + w * 1024 + lane * 16,
                   (char*)xring + ((tt + 3) & 3) * 1536 + w * 1024);
    }
    // ---- phase A (all 16 waves): out = Whh · h via MFMA ----
    f32x4 a0 = {0.f, 0.f, 0.f, 0.f};
    f32x4 a1 = {0.f, 0.f, 0.f, 0.f};
    f32x4 a2 = {0.f, 0.f, 0.f, 0.f};
#pragma unroll
    for (int kt = 0; kt < 8; kt++) {
      half8 bfr = ((const half8*)hsh)[4 * kt + g4];   // broadcast, col-indep
      a0 = __builtin_amdgcn_mfma_f32_16x16x32_f16(afr[0][kt], bfr, a0, 0, 0, 0);
      a1 = __builtin_amdgcn_mfma_f32_16x16x32_f16(afr[1][kt], bfr, a1, 0, 0, 0);
      a2 = __builtin_amdgcn_mfma_f32_16x16x32_f16(afr[2][kt], bfr, a2, 0, 0, 0);
    }
    if (l15 == 0) {   // col-0 lanes hold D[4*g4+r][0] = out[m0+4*g4+r]
      int mb = 4 * g4;
      *(f32x4*)(out_lds + (3 * w + 0) * 16 + mb) = a0;
      *(f32x4*)(out_lds + (3 * w + 1) * 16 + mb) = a1;
      *(f32x4*)(out_lds + (3 * w + 2) * 16 + mb) = a2;
    }
    // staging waves: ensure slot tt&3 has landed (3 newest may be in flight)
    if (w < 2) asm volatile("s_waitcnt vmcnt(3)" ::: "memory");
    lds_barrier();
    // ---- phase B (tid<256, one wave per SIMD): gates ----
    if (tid < 256) {
      int t = dir ? 511 - tt : tt;
      int lab = labsh[t];
      const float* rs = rowsh + lab * 768;
      const unsigned short* xr16 = xring + (tt & 3) * 768;
      float xr = rs[ch]       + b2f(xr16[ch]);
      float xz = rs[256 + ch] + b2f(xr16[256 + ch]);
      float xn = rs[512 + ch] + b2f(xr16[512 + ch]);
      float rg = 1.f / (1.f + __expf(-(xr + out_lds[ch])));        // bhh_r folded
      float zg = 1.f / (1.f + __expf(-(xz + out_lds[256 + ch])));  // bhh_z folded
      float targ = xn + rg * (out_lds[512 + ch] + bh2);
      float e2 = __expf(2.f * targ);
      float ng = 1.f - 2.f / (e2 + 1.f);
      float hnew = (1.f - zg) * ng + zg * hprev;
      hprev = hnew;
      hsh[ch] = (_Float16)hnew;
    }
    lds_barrier();
  }
  if (tid < 256) hbuf[((long)(dir * 88 + n)) * Hh + ch] = hprev;
}

// ---------- final head ----------
__global__ __launch_bounds__(256) void head_kernel(
    const float* __restrict__ hbuf, const void* __restrict__ W1,
    const void* __restrict__ b1, void* __restrict__ out,
    const int* __restrict__ flags)
{
  int flag = flags[0];
  int n = blockIdx.x;
  int c = threadIdx.x;
  float v = hbuf[(long)n * Hh + c] * ldg_any(W1, c, flag)
          + hbuf[(long)(88 + n) * Hh + c] * ldg_any(W1, 256 + c, flag);
  for (int o = 32; o > 0; o >>= 1) v += __shfl_down(v, o);
  __shared__ float red[4];
  if ((c & 63) == 0) red[c >> 6] = v;
  __syncthreads();
  if (c == 0) {
    float s = red[0] + red[1] + red[2] + red[3] + ldg_any(b1, 0, flag);
    float sig = 1.f / (1.f + __expf(-s));
    int k = n / Bb, b = n - k * Bb;
    int o = b * NATT + k;
    if (flag) ((float*)out)[o] = sig;
    else      stf((bf16*)out + o, sig);
  }
}

extern "C" void kernel_launch(void* const* d_in, const int* in_sizes, int n_in,
                              void* d_out, int out_size, void* d_ws, size_t ws_size,
                              hipStream_t stream) {
  const void* labels = d_in[0];
  const void* seq  = d_in[1];
  const void* emb  = d_in[2];
  const void* Wq   = d_in[3];
  const void* bq   = d_in[4];
  const void* Wk   = d_in[5];
  const void* bk   = d_in[6];
  const void* Wv   = d_in[7];
  const void* bv   = d_in[8];
  const void* Wih  = d_in[9];
  const void* Whh  = d_in[10];
  const void* bih  = d_in[11];
  const void* bhh  = d_in[12];
  const void* W1   = d_in[13];
  const void* b1   = d_in[14];

  char* p = (char*)d_ws;
  size_t off = 0;
  auto alloc = [&](size_t bytes) -> void* {
    void* r = p + off; off += (bytes + 255) & ~(size_t)255; return r;
  };
  int*    flags  = (int*)alloc(2 * sizeof(int));
  bf16*   seqb   = (bf16*)alloc(4096UL * 768 * 2);
  float*  qmask7 = (float*)alloc(7 * 4);
  float*  Qsmall = (float*)alloc(11UL * 7 * 768 * 4);
  bf16*   WihB   = (bf16*)alloc(2UL * WSLICE * 2);
  bf16*   WT     = (bf16*)alloc(22UL * WSLICE * 2);
  unsigned short* Kb = (unsigned short*)alloc(11UL * 4096 * 768 * 2);
  unsigned short* Vt = (unsigned short*)alloc(11UL * 768 * 4096 * 2);
  bf16*   outsm  = (bf16*)alloc(768UL * 768 * 2);
  float*  PVW    = (float*)alloc(2UL * 768 * 768 * 4);
  bf16*   seqW   = (bf16*)alloc(2UL * 4096 * 768 * 2);
  float*  hbuf   = (float*)alloc(2UL * 88 * 256 * 4);
  float*  cbias  = (float*)alloc(2UL * 768 * 4);
  if (off > ws_size) return;

  probe_kernel<<<1, 64, 0, stream>>>((const unsigned short*)seq,
                                     (const unsigned*)labels, flags);
  conv_seq_kernel<<<4096, 256, 0, stream>>>(seq, seqb, flags);
  convert_kernel<<<(int)((2 * WSLICE + 255) / 256), 256, 0, stream>>>(
      Wih, WihB, 2L * WSLICE, flags);
  cbias_kernel<<<6, 256, 0, stream>>>(bih, bhh, cbias, flags);
  smalls_kernel<<<dim3(12, 11), 256, 0, stream>>>(emb, Wq, bq, Qsmall, flags);
  emb_copy_kernel<<<7, 256, 0, stream>>>(emb, outsm, qmask7, flags);
  transpose2_kernel<<<dim3(24, 24, 22), 256, 0, stream>>>(Wk, Wv, WT, flags);
  proj_kernel<<<dim3(6, 32, 24), 256, 0, stream>>>(
      seqb, WT, bk, bv, WihB, cbias, Kb, Vt, seqW, flags);
  const float scl = 1.f / sqrtf(768.f);
  attn_kernel<<<88, 512, 0, stream>>>(Kb, Vt, Qsmall, qmask7, outsm, scl);
  pvw_kernel<<<dim3(6, 6, 2), 256, 0, stream>>>(outsm, WihB, PVW, flags);
  gru_kernel<<<176, 1024, 0, stream>>>(seqW, PVW, labels, Whh, bhh, hbuf, flags);
  head_kernel<<<88, 256, 0, stream>>>(hbuf, W1, b1, d_out, flags);
}

// Round 7
// 1497.068 us; speedup vs baseline: 1.3232x; 1.3232x over previous
//
#include <hip/hip_runtime.h>
#include <hip/hip_bf16.h>
#include <hip/hip_fp16.h>
#include <math.h>

typedef __hip_bfloat16 bf16;
typedef __attribute__((ext_vector_type(8))) short short8;
typedef __attribute__((ext_vector_type(4))) float f32x4;
typedef __attribute__((ext_vector_type(8))) _Float16 half8;
typedef __attribute__((ext_vector_type(4))) unsigned u32x4;

#define NATT 11
#define Bb 8
#define Ss 512
#define Dd 768
#define Hh 256
#define WSLICE 589824L  // 768*768

__device__ __forceinline__ void stf(float* p, float v) { *p = v; }
__device__ __forceinline__ void stf(bf16* p, float v) { *p = __float2bfloat16(v); }

__device__ __forceinline__ float blo(unsigned u) { return __uint_as_float(u << 16); }
__device__ __forceinline__ float bhi(unsigned u) { return __uint_as_float(u & 0xffff0000u); }
__device__ __forceinline__ float b2f(unsigned short u) { return __uint_as_float(((unsigned)u) << 16); }

__device__ __forceinline__ float ldg_any(const void* base, long idx, int flag) {
  if (flag) return ((const float*)base)[idx];
  return __bfloat162float(((const bf16*)base)[idx]);
}

__device__ __forceinline__ unsigned packh2(float a, float b) {
  __half2 hh = __floats2half2_rn(a, b);
  return __builtin_bit_cast(unsigned, hh);
}
__device__ __forceinline__ unsigned short f2h(float v) {
  __half h = __float2half(v);
  return __builtin_bit_cast(unsigned short, h);
}

typedef _Float16 f16x2 __attribute__((ext_vector_type(2)));

__device__ __forceinline__ float dot2u(unsigned a, unsigned b, float c) {
#if __has_builtin(__builtin_amdgcn_fdot2)
  return __builtin_amdgcn_fdot2(__builtin_bit_cast(f16x2, a),
                                __builtin_bit_cast(f16x2, b), c, false);
#else
  __half2 ah = __builtin_bit_cast(__half2, a);
  __half2 bh = __builtin_bit_cast(__half2, b);
  float2 af = __half22float2(ah), bf = __half22float2(bh);
  return c + af.x * bf.x + af.y * bf.y;
#endif
}

// barrier that drains ONLY LDS (lgkmcnt) — leaves global prefetches in flight.
__device__ __forceinline__ void lds_barrier() {
  asm volatile("s_waitcnt lgkmcnt(0)\n\ts_barrier" ::: "memory");
}

__device__ __forceinline__ void load_lds16(const void* g, void* l) {
  __builtin_amdgcn_global_load_lds(
      (const __attribute__((address_space(1))) unsigned int*)g,
      (__attribute__((address_space(3))) unsigned int*)l, 16, 0, 0);
}

// ---------- dtype probe ----------
__global__ __launch_bounds__(64) void probe_kernel(
    const unsigned short* __restrict__ sequ, const unsigned* __restrict__ labu,
    int* __restrict__ flags)
{
  int t = threadIdx.x;
  int wild = 0;
#pragma unroll
  for (int i = 0; i < 4; i++) {
    unsigned short v = sequ[t + i * 64];
    int e = (v >> 7) & 0xFF;
    if (e < 90 || e > 160) wild++;
  }
  int nzodd = 0;
#pragma unroll
  for (int i = 0; i < 2; i++) {
    unsigned w = labu[(t + i * 64) * 2 + 1];
    if (w != 0) nzodd++;
  }
  for (int o = 32; o > 0; o >>= 1) {
    wild  += __shfl_down(wild, o);
    nzodd += __shfl_down(nzodd, o);
  }
  if (t == 0) {
    flags[0] = (wild > 32) ? 1 : 0;
    flags[1] = (nzodd == 0) ? 1 : 0;
  }
}

// ---------- seq -> bf16 ----------
__global__ __launch_bounds__(256) void conv_seq_kernel(
    const void* __restrict__ seq, bf16* __restrict__ seqb,
    const int* __restrict__ flags)
{
  int flag = flags[0];
  long row = blockIdx.x;
#pragma unroll
  for (int i = 0; i < 3; i++) {
    long e = row * Dd + threadIdx.x + i * 256;
    seqb[e] = __float2bfloat16(ldg_any(seq, e, flag));
  }
}

// ---------- generic convert to bf16 (Wih) ----------
__global__ __launch_bounds__(256) void convert_kernel(
    const void* __restrict__ src, bf16* __restrict__ dst, long n,
    const int* __restrict__ flags)
{
  int flag = flags[0];
  long i = (long)blockIdx.x * 256 + threadIdx.x;
  if (i < n) dst[i] = __float2bfloat16(ldg_any(src, i, flag));
}

// ---------- cbias[2][768] = bih + (col<512 ? bhh : 0)  (f32) ----------
__global__ __launch_bounds__(256) void cbias_kernel(
    const void* __restrict__ bih, const void* __restrict__ bhh,
    float* __restrict__ cbias, const int* __restrict__ flags)
{
  int flag = flags[0];
  int i = blockIdx.x * 256 + threadIdx.x;  // grid 6 -> 1536
  int c = i & 767;
  float v = ldg_any(bih, i, flag);
  if (c < 512) v += ldg_any(bhh, i, flag);
  cbias[i] = v;
}

// ---------- Qsmall[11][7][768] = relu(emb7 @ Wq + bq); grid (12, 11) ----------
__global__ __launch_bounds__(256) void smalls_kernel(
    const void* __restrict__ emb, const void* __restrict__ Wq,
    const void* __restrict__ bq, float* __restrict__ Qsmall,
    const int* __restrict__ flags)
{
  int flag = flags[0];
  __shared__ float embsh[7 * 768];
  __shared__ float psum[4][7][64];
  int z = blockIdx.y;
  int bx = blockIdx.x;
  int tid = threadIdx.x;
  int sub = tid >> 6, nl = tid & 63;
  for (int i = tid; i < 7 * 768; i += 256) embsh[i] = ldg_any(emb, i, flag);
  __syncthreads();
  int n = bx * 64 + nl;
  long base = (long)z * WSLICE;
  float acc[7] = {};
  int e0 = sub * 192;
  for (int e = e0; e < e0 + 192; e++) {
    float wv = ldg_any(Wq, base + (long)e * Dd + n, flag);
#pragma unroll
    for (int l = 0; l < 7; l++) acc[l] += embsh[l * 768 + e] * wv;
  }
#pragma unroll
  for (int l = 0; l < 7; l++) psum[sub][l][nl] = acc[l];
  __syncthreads();
  if (sub == 0) {
    float bv = ldg_any(bq, z * Dd + n, flag);
#pragma unroll
    for (int l = 0; l < 7; l++) {
      float v = psum[0][l][nl] + psum[1][l][nl] + psum[2][l][nl] + psum[3][l][nl] + bv;
      Qsmall[((long)z * 7 + l) * Dd + n] = fmaxf(v, 0.f);
    }
  }
}

// ---------- emb rows -> outsm[640+l] (bf16) + qmask7 ----------
__global__ __launch_bounds__(256) void emb_copy_kernel(
    const void* __restrict__ emb, bf16* __restrict__ outsm,
    float* __restrict__ qmask7, const int* __restrict__ flags)
{
  int flag = flags[0];
  int l = blockIdx.x;
  int t = threadIdx.x;
  float s = 0.f;
#pragma unroll
  for (int i = 0; i < 3; i++) {
    int e = t + i * 256;
    float v = ldg_any(emb, (long)l * Dd + e, flag);
    outsm[(long)(640 + l) * Dd + e] = __float2bfloat16(v);
    s += v;
  }
  for (int o = 32; o > 0; o >>= 1) s += __shfl_down(s, o);
  __shared__ float red[4];
  if ((t & 63) == 0) red[t >> 6] = s;
  __syncthreads();
  if (t == 0) {
    float tot = red[0] + red[1] + red[2] + red[3];
    qmask7[l] = (tot != 0.f) ? 1.f : 0.f;
  }
}

// ---------- transpose Wk/Wv branch slices to [N][K] bf16 ----------
__global__ __launch_bounds__(256) void transpose2_kernel(
    const void* __restrict__ Wk, const void* __restrict__ Wv,
    bf16* __restrict__ WT, const int* __restrict__ flags)
{
  int flag = flags[0];
  __shared__ float tile[32][33];
  int z = blockIdx.z;
  int m = z >> 1, wsel = z & 1;
  const void* src = wsel ? Wv : Wk;
  long off = (long)m * WSLICE;
  bf16* dst = WT + (long)z * WSLICE;
  int kk0 = blockIdx.y * 32, n0 = blockIdx.x * 32;
  int tx = threadIdx.x & 31, ty = threadIdx.x >> 5;
#pragma unroll
  for (int i = 0; i < 4; i++)
    tile[ty + i * 8][tx] = ldg_any(src, off + (long)(kk0 + ty + i * 8) * Dd + n0 + tx, flag);
  __syncthreads();
#pragma unroll
  for (int i = 0; i < 4; i++)
    dst[(long)(n0 + ty + i * 8) * Dd + kk0 + tx] = __float2bfloat16(tile[tx][ty + i * 8]);
}

// ---------- MFMA GEMM core: C = epi(scale*A@B^T) ----------
// cMode: 0=bf16, 2=fp32, 3=fp16, 5=fp16 transposed via LDS bounce (coalesced).
// cMode 5 REQUIRES As,Bs to be one contiguous 16KB block.
__device__ __forceinline__ void gemm_mfma_core(
    const bf16* __restrict__ Ab, long ldA,
    const bf16* __restrict__ Bbp, long ldB,
    bf16* As, bf16* Bs, int bm, int bn, int K,
    const void* bias, long bOff,
    void* C, long ldC, int cMode,
    float scale, int relu, int fflag)
{
  int tid = threadIdx.x;
  int lane = tid & 63, w = tid >> 6;
  int mo = (w & 1) * 64, no = (w >> 1) * 64;
  int l15 = lane & 15, q4 = lane >> 4;
  int gr = lane >> 2;
  int gs = (lane & 3) * 8;
  const bf16* aS0 = Ab + (long)(bm + w * 16 + gr) * ldA + gs;
  const bf16* aS1 = aS0 + 64 * ldA;
  const bf16* bS0 = Bbp + (long)(bn + w * 16 + gr) * ldB + gs;
  const bf16* bS1 = bS0 + 64 * ldB;
  bf16* aD0 = As + w * 512;
  bf16* aD1 = As + 2048 + w * 512;
  bf16* bD0 = Bs + w * 512;
  bf16* bD1 = Bs + 2048 + w * 512;

  f32x4 acc[4][4];
#pragma unroll
  for (int i = 0; i < 4; i++)
#pragma unroll
    for (int j = 0; j < 4; j++)
#pragma unroll
      for (int r = 0; r < 4; r++) acc[i][j][r] = 0.f;

  for (int k0 = 0; k0 < K; k0 += 32) {
    load_lds16(aS0, aD0);
    load_lds16(aS1, aD1);
    load_lds16(bS0, bD0);
    load_lds16(bS1, bD1);
    aS0 += 32; aS1 += 32; bS0 += 32; bS1 += 32;
    __syncthreads();
    short8 af[4], bfv[4];
#pragma unroll
    for (int i = 0; i < 4; i++)
      af[i] = *(const short8*)(As + (mo + i * 16 + l15) * 32 + q4 * 8);
#pragma unroll
    for (int j = 0; j < 4; j++)
      bfv[j] = *(const short8*)(Bs + (no + j * 16 + l15) * 32 + q4 * 8);
#pragma unroll
    for (int i = 0; i < 4; i++)
#pragma unroll
      for (int j = 0; j < 4; j++)
        acc[i][j] = __builtin_amdgcn_mfma_f32_16x16x32_bf16(af[i], bfv[j], acc[i][j], 0, 0, 0);
    __syncthreads();
  }

  float bsv[4];
#pragma unroll
  for (int j = 0; j < 4; j++) {
    int colg = bn + no + j * 16 + l15;
    bsv[j] = bias ? ldg_any(bias, bOff + colg, fflag) : 0.f;
  }

  if (cMode == 5) {
    unsigned short* tile = (unsigned short*)As;   // [32][136]
    int cl = (no >> 6) * 16 + l15;
#pragma unroll
    for (int j = 0; j < 4; j++) {
      __syncthreads();
#pragma unroll
      for (int i = 0; i < 4; i++) {
#pragma unroll
        for (int r = 0; r < 4; r++) {
          float v = acc[i][j][r] * scale + bsv[j];
          if (relu) v = fmaxf(v, 0.f);
          tile[cl * 136 + mo + i * 16 + q4 * 4 + r] = f2h(v);
        }
      }
      __syncthreads();
#pragma unroll
      for (int uu = 0; uu < 2; uu++) {
        int u = tid + uu * 256;
        int c = u >> 4, mseg = u & 15;
        int colg = bn + (c >> 4) * 64 + j * 16 + (c & 15);
        uint2 v0 = *(const uint2*)(tile + c * 136 + mseg * 8);
        uint2 v1 = *(const uint2*)(tile + c * 136 + mseg * 8 + 4);
        uint4 pk; pk.x = v0.x; pk.y = v0.y; pk.z = v1.x; pk.w = v1.y;
        *(uint4*)((unsigned short*)C + (long)colg * ldC + bm + mseg * 8) = pk;
      }
    }
    return;
  }

#pragma unroll
  for (int i = 0; i < 4; i++) {
#pragma unroll
    for (int j = 0; j < 4; j++) {
      int colg = bn + no + j * 16 + l15;
#pragma unroll
      for (int r = 0; r < 4; r++) {
        int rowg = bm + mo + i * 16 + q4 * 4 + r;
        float v = acc[i][j][r] * scale + bsv[j];
        if (relu) v = fmaxf(v, 0.f);
        long off2 = (long)rowg * ldC + colg;
        if (cMode == 2)      ((float*)C)[off2] = v;
        else if (cMode == 3) ((unsigned short*)C)[off2] = f2h(v);
        else                 ((bf16*)C)[off2] = __float2bfloat16(v);
      }
    }
  }
}

// ---------- K/V projections + seqW, z: 0..21 = m*2+{K,V}; 22,23 = seqW dir ----------
__global__ __launch_bounds__(256, 2) void proj_kernel(
    const bf16* __restrict__ seqb, const bf16* __restrict__ WT,
    const void* __restrict__ bk, const void* __restrict__ bv,
    const bf16* __restrict__ WihB, const float* __restrict__ cbias,
    unsigned short* __restrict__ Kb, unsigned short* __restrict__ Vt,
    bf16* __restrict__ seqW, const int* __restrict__ flags)
{
  __shared__ __align__(16) bf16 smem[8192];   // contiguous As+Bs (cMode 5 needs this)
  bf16* As = smem;
  bf16* Bs = smem + 4096;
  int z = blockIdx.z;
  if (z < 22) {
    int m = z >> 1, wsel = z & 1;
    const bf16* B = WT + (long)z * WSLICE;
    if (wsel == 0) {
      gemm_mfma_core(seqb, Dd, B, Dd, As, Bs, blockIdx.y * 128, blockIdx.x * 128, Dd,
                     bk, (long)m * Dd, Kb + (long)m * 4096 * Dd, Dd, 3, 1.f, 1, flags[0]);
    } else {
      gemm_mfma_core(seqb, Dd, B, Dd, As, Bs, blockIdx.y * 128, blockIdx.x * 128, Dd,
                     bv, (long)m * Dd, Vt + (long)m * Dd * 4096, 4096, 5, 1.f, 1, flags[0]);
    }
  } else {
    int dir = z - 22;
    // bias = bih + bhh(r,z) precomputed in f32 (fflag=1)
    gemm_mfma_core(seqb, Dd, WihB + (long)dir * WSLICE, Dd, As, Bs,
                   blockIdx.y * 128, blockIdx.x * 128, Dd,
                   cbias, (long)dir * Dd, seqW + (long)dir * 4096 * Dd, Dd, 0,
                   1.f, 0, 1);
  }
}

// ---------- PVW = outsm(768 rows incl emb @640) @ Wih^T (fp32), z = dir ----------
__global__ __launch_bounds__(256, 2) void pvw_kernel(
    const bf16* __restrict__ outsm, const bf16* __restrict__ WihB,
    float* __restrict__ PVW, const int* __restrict__ flags)
{
  __shared__ __align__(16) bf16 As[4096];
  __shared__ __align__(16) bf16 Bs[4096];
  int dir = blockIdx.z;
  gemm_mfma_core(outsm, Dd, WihB + (long)dir * WSLICE, Dd, As, Bs,
                 blockIdx.y * 128, blockIdx.x * 128, Dd,
                 nullptr, 0, PVW + (long)dir * 768 * Dd, Dd, 2, 1.f, 0, flags[0]);
}

// ---------- fused scores+softmax+mask+PV per (k,b) ----------
__global__ __launch_bounds__(512, 2) void attn_kernel(
    const unsigned short* __restrict__ Kb, const unsigned short* __restrict__ Vt,
    const float* __restrict__ Qsmall, const float* __restrict__ qmask7,
    bf16* __restrict__ outsm, float scl)
{
  int blk = blockIdx.x;  // k*8+b
  int k = blk >> 3, b = blk & 7;
  int tid = threadIdx.x;
  int lane = tid & 63, w = tid >> 6;
  __shared__ unsigned qs[7][384];
  __shared__ unsigned short ash[7][512];
  __shared__ float wred[8][7];
  __shared__ float gred[7];
  __shared__ float finv[7];
  for (int i = tid; i < 7 * 384; i += 512) {
    int l = i / 384, e2 = i - l * 384;
    const float* qp = Qsmall + ((long)k * 7 + l) * Dd + 2 * e2;
    qs[l][e2] = packh2(qp[0], qp[1]);
  }
  __syncthreads();
  const uint4* Krow = (const uint4*)(Kb + ((long)k * 4096 + b * 512 + tid) * Dd);
  float sc[7] = {};
  for (int e8 = 0; e8 < 96; e8++) {
    uint4 kv = Krow[e8];
#pragma unroll
    for (int l = 0; l < 7; l++) {
      sc[l] = dot2u(qs[l][e8 * 4],     kv.x, sc[l]);
      sc[l] = dot2u(qs[l][e8 * 4 + 1], kv.y, sc[l]);
      sc[l] = dot2u(qs[l][e8 * 4 + 2], kv.z, sc[l]);
      sc[l] = dot2u(qs[l][e8 * 4 + 3], kv.w, sc[l]);
    }
  }
#pragma unroll
  for (int l = 0; l < 7; l++) sc[l] *= scl;
#pragma unroll
  for (int l = 0; l < 7; l++) {
    float v = sc[l];
    for (int o = 32; o > 0; o >>= 1) v = fmaxf(v, __shfl_down(v, o));
    if (lane == 0) wred[w][l] = v;
  }
  __syncthreads();
  if (tid < 7) {
    float m = wred[0][tid];
#pragma unroll
    for (int i = 1; i < 8; i++) m = fmaxf(m, wred[i][tid]);
    gred[tid] = m;
  }
  __syncthreads();
  float ev[7];
#pragma unroll
  for (int l = 0; l < 7; l++) {
    ev[l] = __expf(sc[l] - gred[l]);
    float v = ev[l];
    for (int o = 32; o > 0; o >>= 1) v += __shfl_down(v, o);
    if (lane == 0) wred[w][l] = v;
  }
  __syncthreads();
  if (tid < 7) {
    float s = 0.f;
#pragma unroll
    for (int i = 0; i < 8; i++) s += wred[i][tid];
    finv[tid] = qmask7[tid] / s;
  }
  __syncthreads();
#pragma unroll
  for (int l = 0; l < 7; l++) ash[l][tid] = f2h(ev[l] * finv[l]);
  __syncthreads();
  for (int rep = 0; rep < 2; rep++) {
    int n = tid + rep * 512;
    if (n >= Dd) break;
    const uint4* Vrow = (const uint4*)(Vt + ((long)k * Dd + n) * 4096 + b * 512);
    float acc[7] = {};
    for (int m8 = 0; m8 < 64; m8++) {
      uint4 vv = Vrow[m8];
#pragma unroll
      for (int l = 0; l < 7; l++) {
        const unsigned* ap = (const unsigned*)&ash[l][0];
        acc[l] = dot2u(ap[m8 * 4],     vv.x, acc[l]);
        acc[l] = dot2u(ap[m8 * 4 + 1], vv.y, acc[l]);
        acc[l] = dot2u(ap[m8 * 4 + 2], vv.z, acc[l]);
        acc[l] = dot2u(ap[m8 * 4 + 3], vv.w, acc[l]);
      }
    }
#pragma unroll
    for (int l = 0; l < 7; l++)
      outsm[((long)blk * 7 + l) * Dd + n] = __float2bfloat16(acc[l]);
  }
}

// ---------- GRU v14: AGPR asm MFMA with hazard-closed groups ----------
// v13 post-mortem: absmax 2.7e-2 (v11/v12 same math passed) => raw-asm
// hazard. The AMDGPU hazard recognizer can't see inside inline asm, so
// allocator-inserted VALU copies (tuple-alignment v_mov / v_accvgpr)
// directly before an asm MFMA violate the 2-wait-state
// "VALU write -> MFMA read SrcA/B/C" rule. Fix: one asm volatile block
// per kt = "s_nop 1" + 6 MFMAs. The leading s_nop guards any preceding
// compiler VALU; nothing can interleave within a block; between blocks
// the only compiler code is the next bfr ds_read whose write-back lands
// >=60 cyc after any aliasing MFMA read (outside all hazard windows).
// Trailing 3x s_nop 7 (24 cyc) before the acc ds_write covers
// MFMA-D -> VALU/DS read. Cost: 8x2 cyc/step. Structure = v13/v11.
__global__ __launch_bounds__(512) void gru_kernel(
    const bf16* __restrict__ seqW,   // [2][4096][768] bf16, includes bih + bhh(r,z)
    const float* __restrict__ PVW,   // [2][768][768]; rows n*7+l and 640+l(emb)
    const void* __restrict__ labels,
    const void* __restrict__ Whh, const void* __restrict__ bhh,
    float* __restrict__ hbuf, const int* __restrict__ flags)
{
  int flag = flags[0], lflag = flags[1];
  int idx = blockIdx.x;
  int dir = idx / 88, n = idx - dir * 88;
  int b = n & 7;
  int tid = threadIdx.x;
  int lane = tid & 63, w = tid >> 6;
  int l15 = lane & 15, g4 = lane >> 4;

  // A-fragments: tile t6 (gate g=t6>>1, half hb=t6&1): rows m0..m0+15,
  // m0 = g*256 + 32w + 16*hb. Lane holds W[m0+l15][32kt + 8*g4 + j].
  // u32x4 (4 regs); all uses are "a"-constrained asm -> AGPR-resident.
  u32x4 afr[6][8];
#pragma unroll
  for (int t = 0; t < 6; t++) {
    int m0 = (t >> 1) * 256 + 32 * w + (t & 1) * 16;
    long rb = ((long)dir * Dd + m0 + l15) * (long)Hh + 8 * g4;
#pragma unroll
    for (int kt = 0; kt < 8; kt++) {
      long eb = rb + 32 * kt;
      u32x4 u;
      if (flag) {
        const float4* s4 = (const float4*)((const float*)Whh + eb);
        float4 v0 = s4[0], v1 = s4[1];
        u[0] = packh2(v0.x, v0.y); u[1] = packh2(v0.z, v0.w);
        u[2] = packh2(v1.x, v1.y); u[3] = packh2(v1.z, v1.w);
      } else {
        uint4 v = *(const uint4*)((const bf16*)Whh + eb);
        u[0] = packh2(blo(v.x), bhi(v.x));
        u[1] = packh2(blo(v.y), bhi(v.y));
        u[2] = packh2(blo(v.z), bhi(v.z));
        u[3] = packh2(blo(v.w), bhi(v.w));
      }
      afr[t][kt] = u;
    }
  }

  __shared__ float rowsh[7 * 768];
  __shared__ int labsh[512];
  __shared__ __align__(16) float out_lds[768];
  __shared__ __align__(16) _Float16 hsh[256];
  __shared__ __align__(16) unsigned short xring[4 * 768];  // 4-deep x-row ring

  for (int i = tid; i < 7 * 768; i += 512) {
    int l = i / 768, row = i - l * 768;
    rowsh[i] = PVW[((long)dir * 768 + n * 7 + l) * Dd + row]
             + PVW[((long)dir * 768 + 640 + l) * Dd + row];
  }
  labsh[tid] = lflag ? (int)((const long long*)labels)[b * 512 + tid]
                     : ((const int*)labels)[b * 512 + tid];
  if (tid < 256) hsh[tid] = (_Float16)0.f;

  int ch = tid & 255;
  float bh2 = 0.f, hprev = 0.f;
  if (tid < 256) bh2 = ldg_any(bhh, dir * Dd + 512 + ch, flag);

  // x-row DMA: row t is 1536 B; wave0 lanes 0-63 cover bytes 0..1023,
  // wave1 lanes 0-31 cover 1024..1535 (LDS dst = uniform base + lane*16).
  const char* swb = (const char*)seqW + ((long)dir * 4096 + b * 512) * (long)(Dd * 2);
  int dma = (w == 0) || (w == 1 && lane < 32);
  // prime ring slots 0..2
  if (dma) {
#pragma unroll
    for (int s = 0; s < 3; s++) {
      int tp = dir ? 511 - s : s;
      load_lds16(swb + (long)tp * 1536 + w * 1024 + lane * 16,
                 (char*)xring + s * 1536 + w * 1024);
    }
  }
  __syncthreads();   // drains vmcnt(0)+lgkmcnt(0): ring 0..2 ready, hsh ready

  for (int tt = 0; tt < Ss; tt++) {
    // issue DMA for step tt+3 (slot (tt+3)&3); clamped row at the tail
    {
      int ttp = (tt + 3 < Ss) ? tt + 3 : Ss - 1;
      int tp = dir ? 511 - ttp : ttp;
      if (dma)
        load_lds16(swb + (long)tp * 1536 + w * 1024 + lane * 16,
                   (char*)xring + ((tt + 3) & 3) * 1536 + w * 1024);
    }
    // ---- phase A (all 8 waves): out = Whh · h via asm MFMA (A from AGPR) ----
    f32x4 a0 = {0.f, 0.f, 0.f, 0.f};
    f32x4 a1 = {0.f, 0.f, 0.f, 0.f};
    f32x4 a2 = {0.f, 0.f, 0.f, 0.f};
    f32x4 a3 = {0.f, 0.f, 0.f, 0.f};
    f32x4 a4 = {0.f, 0.f, 0.f, 0.f};
    f32x4 a5 = {0.f, 0.f, 0.f, 0.f};
#pragma unroll
    for (int kt = 0; kt < 8; kt++) {
      half8 bfr = ((const half8*)hsh)[4 * kt + g4];   // broadcast, col-indep
      // one asm block per kt: leading s_nop 1 guards any compiler VALU
      // (acc-init movs, tuple-align copies) against SrcA/B/C reads; the
      // 6 MFMAs are contiguous so nothing interleaves.
      asm volatile(
          "s_nop 1\n\t"
          "v_mfma_f32_16x16x32_f16 %0, %6, %12, %0\n\t"
          "v_mfma_f32_16x16x32_f16 %1, %7, %12, %1\n\t"
          "v_mfma_f32_16x16x32_f16 %2, %8, %12, %2\n\t"
          "v_mfma_f32_16x16x32_f16 %3, %9, %12, %3\n\t"
          "v_mfma_f32_16x16x32_f16 %4, %10, %12, %4\n\t"
          "v_mfma_f32_16x16x32_f16 %5, %11, %12, %5"
          : "+v"(a0), "+v"(a1), "+v"(a2), "+v"(a3), "+v"(a4), "+v"(a5)
          : "a"(afr[0][kt]), "a"(afr[1][kt]), "a"(afr[2][kt]),
            "a"(afr[3][kt]), "a"(afr[4][kt]), "a"(afr[5][kt]),
            "v"(bfr));
    }
    // MFMA D write -> VALU/LDS read of acc: generous 24-cycle guard
    asm volatile("s_nop 7\n\ts_nop 7\n\ts_nop 7"
        : "+v"(a0), "+v"(a1), "+v"(a2), "+v"(a3), "+v"(a4), "+v"(a5));
    if (l15 == 0) {   // col-0 lanes hold D[4*g4+r][0] = out[m0+4*g4+r]
      int mb = 32 * w + 4 * g4;
      *(f32x4*)(out_lds + mb)            = a0;   // t6=0: g0, hb0
      *(f32x4*)(out_lds + mb + 16)       = a1;   // t6=1: g0, hb1
      *(f32x4*)(out_lds + 256 + mb)      = a2;   // t6=2: g1, hb0
      *(f32x4*)(out_lds + 256 + mb + 16) = a3;   // t6=3: g1, hb1
      *(f32x4*)(out_lds + 512 + mb)      = a4;   // t6=4: g2, hb0
      *(f32x4*)(out_lds + 512 + mb + 16) = a5;   // t6=5: g2, hb1
    }
    // staging waves: ensure slot tt&3 has landed (3 newest may be in flight)
    if (w < 2) asm volatile("s_waitcnt vmcnt(3)" ::: "memory");
    lds_barrier();
    // ---- phase B (tid<256): gates ----
    if (tid < 256) {
      int t = dir ? 511 - tt : tt;
      int lab = labsh[t];
      const float* rs = rowsh + lab * 768;
      const unsigned short* xr16 = xring + (tt & 3) * 768;
      float xr = rs[ch]       + b2f(xr16[ch]);
      float xz = rs[256 + ch] + b2f(xr16[256 + ch]);
      float xn = rs[512 + ch] + b2f(xr16[512 + ch]);
      float rg = 1.f / (1.f + __expf(-(xr + out_lds[ch])));        // bhh_r folded
      float zg = 1.f / (1.f + __expf(-(xz + out_lds[256 + ch])));  // bhh_z folded
      float targ = xn + rg * (out_lds[512 + ch] + bh2);
      float e2 = __expf(2.f * targ);
      float ng = 1.f - 2.f / (e2 + 1.f);
      float hnew = (1.f - zg) * ng + zg * hprev;
      hprev = hnew;
      hsh[ch] = (_Float16)hnew;
    }
    lds_barrier();
  }
  if (tid < 256) hbuf[((long)(dir * 88 + n)) * Hh + ch] = hprev;
}

// ---------- final head ----------
__global__ __launch_bounds__(256) void head_kernel(
    const float* __restrict__ hbuf, const void* __restrict__ W1,
    const void* __restrict__ b1, void* __restrict__ out,
    const int* __restrict__ flags)
{
  int flag = flags[0];
  int n = blockIdx.x;
  int c = threadIdx.x;
  float v = hbuf[(long)n * Hh + c] * ldg_any(W1, c, flag)
          + hbuf[(long)(88 + n) * Hh + c] * ldg_any(W1, 256 + c, flag);
  for (int o = 32; o > 0; o >>= 1) v += __shfl_down(v, o);
  __shared__ float red[4];
  if ((c & 63) == 0) red[c >> 6] = v;
  __syncthreads();
  if (c == 0) {
    float s = red[0] + red[1] + red[2] + red[3] + ldg_any(b1, 0, flag);
    float sig = 1.f / (1.f + __expf(-s));
    int k = n / Bb, b = n - k * Bb;
    int o = b * NATT + k;
    if (flag) ((float*)out)[o] = sig;
    else      stf((bf16*)out + o, sig);
  }
}

extern "C" void kernel_launch(void* const* d_in, const int* in_sizes, int n_in,
                              void* d_out, int out_size, void* d_ws, size_t ws_size,
                              hipStream_t stream) {
  const void* labels = d_in[0];
  const void* seq  = d_in[1];
  const void* emb  = d_in[2];
  const void* Wq   = d_in[3];
  const void* bq   = d_in[4];
  const void* Wk   = d_in[5];
  const void* bk   = d_in[6];
  const void* Wv   = d_in[7];
  const void* bv   = d_in[8];
  const void* Wih  = d_in[9];
  const void* Whh  = d_in[10];
  const void* bih  = d_in[11];
  const void* bhh  = d_in[12];
  const void* W1   = d_in[13];
  const void* b1   = d_in[14];

  char* p = (char*)d_ws;
  size_t off = 0;
  auto alloc = [&](size_t bytes) -> void* {
    void* r = p + off; off += (bytes + 255) & ~(size_t)255; return r;
  };
  int*    flags  = (int*)alloc(2 * sizeof(int));
  bf16*   seqb   = (bf16*)alloc(4096UL * 768 * 2);
  float*  qmask7 = (float*)alloc(7 * 4);
  float*  Qsmall = (float*)alloc(11UL * 7 * 768 * 4);
  bf16*   WihB   = (bf16*)alloc(2UL * WSLICE * 2);
  bf16*   WT     = (bf16*)alloc(22UL * WSLICE * 2);
  unsigned short* Kb = (unsigned short*)alloc(11UL * 4096 * 768 * 2);
  unsigned short* Vt = (unsigned short*)alloc(11UL * 768 * 4096 * 2);
  bf16*   outsm  = (bf16*)alloc(768UL * 768 * 2);
  float*  PVW    = (float*)alloc(2UL * 768 * 768 * 4);
  bf16*   seqW   = (bf16*)alloc(2UL * 4096 * 768 * 2);
  float*  hbuf   = (float*)alloc(2UL * 88 * 256 * 4);
  float*  cbias  = (float*)alloc(2UL * 768 * 4);
  if (off > ws_size) return;

  probe_kernel<<<1, 64, 0, stream>>>((const unsigned short*)seq,
                                     (const unsigned*)labels, flags);
  conv_seq_kernel<<<4096, 256, 0, stream>>>(seq, seqb, flags);
  convert_kernel<<<(int)((2 * WSLICE + 255) / 256), 256, 0, stream>>>(
      Wih, WihB, 2L * WSLICE, flags);
  cbias_kernel<<<6, 256, 0, stream>>>(bih, bhh, cbias, flags);
  smalls_kernel<<<dim3(12, 11), 256, 0, stream>>>(emb, Wq, bq, Qsmall, flags);
  emb_copy_kernel<<<7, 256, 0, stream>>>(emb, outsm, qmask7, flags);
  transpose2_kernel<<<dim3(24, 24, 22), 256, 0, stream>>>(Wk, Wv, WT, flags);
  proj_kernel<<<dim3(6, 32, 24), 256, 0, stream>>>(
      seqb, WT, bk, bv, WihB, cbias, Kb, Vt, seqW, flags);
  const float scl = 1.f / sqrtf(768.f);
  attn_kernel<<<88, 512, 0, stream>>>(Kb, Vt, Qsmall, qmask7, outsm, scl);
  pvw_kernel<<<dim3(6, 6, 2), 256, 0, stream>>>(outsm, WihB, PVW, flags);
  gru_kernel<<<176, 512, 0, stream>>>(seqW, PVW, labels, Whh, bhh, hbuf, flags);
  head_kernel<<<88, 256, 0, stream>>>(hbuf, W1, b1, d_out, flags);
}

// Round 8
// 1198.238 us; speedup vs baseline: 1.6532x; 1.2494x over previous
//
#include <hip/hip_runtime.h>
#include <hip/hip_bf16.h>
#include <hip/hip_fp16.h>
#include <math.h>

typedef __hip_bfloat16 bf16;
typedef __attribute__((ext_vector_type(8))) short short8;
typedef __attribute__((ext_vector_type(4))) float f32x4;
typedef __attribute__((ext_vector_type(8))) _Float16 half8;
typedef __attribute__((ext_vector_type(2))) unsigned u32x2;

#define NATT 11
#define Bb 8
#define Ss 512
#define Dd 768
#define Hh 256
#define WSLICE 589824L  // 768*768

__device__ __forceinline__ void stf(float* p, float v) { *p = v; }
__device__ __forceinline__ void stf(bf16* p, float v) { *p = __float2bfloat16(v); }

__device__ __forceinline__ float blo(unsigned u) { return __uint_as_float(u << 16); }
__device__ __forceinline__ float bhi(unsigned u) { return __uint_as_float(u & 0xffff0000u); }
__device__ __forceinline__ float b2f(unsigned short u) { return __uint_as_float(((unsigned)u) << 16); }

__device__ __forceinline__ float ldg_any(const void* base, long idx, int flag) {
  if (flag) return ((const float*)base)[idx];
  return __bfloat162float(((const bf16*)base)[idx]);
}

__device__ __forceinline__ unsigned packh2(float a, float b) {
  __half2 hh = __floats2half2_rn(a, b);
  return __builtin_bit_cast(unsigned, hh);
}
__device__ __forceinline__ unsigned short f2h(float v) {
  __half h = __float2half(v);
  return __builtin_bit_cast(unsigned short, h);
}

// OCP e4m3 conversions (gfx950 hw format)
__device__ __forceinline__ unsigned cvt4_fp8(float a, float b, float c, float d) {
  unsigned t = (unsigned)__builtin_amdgcn_cvt_pk_fp8_f32(a, b, 0, false);
  t = (unsigned)__builtin_amdgcn_cvt_pk_fp8_f32(c, d, (int)t, true);
  return t;
}
__device__ __forceinline__ unsigned char f2e4m3(float v) {
  return (unsigned char)(unsigned)__builtin_amdgcn_cvt_pk_fp8_f32(v, v, 0, false);
}

typedef _Float16 f16x2 __attribute__((ext_vector_type(2)));

__device__ __forceinline__ float dot2u(unsigned a, unsigned b, float c) {
#if __has_builtin(__builtin_amdgcn_fdot2)
  return __builtin_amdgcn_fdot2(__builtin_bit_cast(f16x2, a),
                                __builtin_bit_cast(f16x2, b), c, false);
#else
  __half2 ah = __builtin_bit_cast(__half2, a);
  __half2 bh = __builtin_bit_cast(__half2, b);
  float2 af = __half22float2(ah), bf = __half22float2(bh);
  return c + af.x * bf.x + af.y * bf.y;
#endif
}

// barrier that drains ONLY LDS (lgkmcnt) — leaves global prefetches in flight.
__device__ __forceinline__ void lds_barrier() {
  asm volatile("s_waitcnt lgkmcnt(0)\n\ts_barrier" ::: "memory");
}

__device__ __forceinline__ void load_lds16(const void* g, void* l) {
  __builtin_amdgcn_global_load_lds(
      (const __attribute__((address_space(1))) unsigned int*)g,
      (__attribute__((address_space(3))) unsigned int*)l, 16, 0, 0);
}

// ---------- dtype probe ----------
__global__ __launch_bounds__(64) void probe_kernel(
    const unsigned short* __restrict__ sequ, const unsigned* __restrict__ labu,
    int* __restrict__ flags)
{
  int t = threadIdx.x;
  int wild = 0;
#pragma unroll
  for (int i = 0; i < 4; i++) {
    unsigned short v = sequ[t + i * 64];
    int e = (v >> 7) & 0xFF;
    if (e < 90 || e > 160) wild++;
  }
  int nzodd = 0;
#pragma unroll
  for (int i = 0; i < 2; i++) {
    unsigned w = labu[(t + i * 64) * 2 + 1];
    if (w != 0) nzodd++;
  }
  for (int o = 32; o > 0; o >>= 1) {
    wild  += __shfl_down(wild, o);
    nzodd += __shfl_down(nzodd, o);
  }
  if (t == 0) {
    flags[0] = (wild > 32) ? 1 : 0;
    flags[1] = (nzodd == 0) ? 1 : 0;
  }
}

// ---------- seq -> bf16 ----------
__global__ __launch_bounds__(256) void conv_seq_kernel(
    const void* __restrict__ seq, bf16* __restrict__ seqb,
    const int* __restrict__ flags)
{
  int flag = flags[0];
  long row = blockIdx.x;
#pragma unroll
  for (int i = 0; i < 3; i++) {
    long e = row * Dd + threadIdx.x + i * 256;
    seqb[e] = __float2bfloat16(ldg_any(seq, e, flag));
  }
}

// ---------- generic convert to bf16 (Wih) ----------
__global__ __launch_bounds__(256) void convert_kernel(
    const void* __restrict__ src, bf16* __restrict__ dst, long n,
    const int* __restrict__ flags)
{
  int flag = flags[0];
  long i = (long)blockIdx.x * 256 + threadIdx.x;
  if (i < n) dst[i] = __float2bfloat16(ldg_any(src, i, flag));
}

// ---------- cbias[2][768] = bih + (col<512 ? bhh : 0)  (f32) ----------
__global__ __launch_bounds__(256) void cbias_kernel(
    const void* __restrict__ bih, const void* __restrict__ bhh,
    float* __restrict__ cbias, const int* __restrict__ flags)
{
  int flag = flags[0];
  int i = blockIdx.x * 256 + threadIdx.x;  // grid 6 -> 1536
  int c = i & 767;
  float v = ldg_any(bih, i, flag);
  if (c < 512) v += ldg_any(bhh, i, flag);
  cbias[i] = v;
}

// ---------- Qsmall[11][7][768] = relu(emb7 @ Wq + bq); grid (12, 11) ----------
__global__ __launch_bounds__(256) void smalls_kernel(
    const void* __restrict__ emb, const void* __restrict__ Wq,
    const void* __restrict__ bq, float* __restrict__ Qsmall,
    const int* __restrict__ flags)
{
  int flag = flags[0];
  __shared__ float embsh[7 * 768];
  __shared__ float psum[4][7][64];
  int z = blockIdx.y;
  int bx = blockIdx.x;
  int tid = threadIdx.x;
  int sub = tid >> 6, nl = tid & 63;
  for (int i = tid; i < 7 * 768; i += 256) embsh[i] = ldg_any(emb, i, flag);
  __syncthreads();
  int n = bx * 64 + nl;
  long base = (long)z * WSLICE;
  float acc[7] = {};
  int e0 = sub * 192;
  for (int e = e0; e < e0 + 192; e++) {
    float wv = ldg_any(Wq, base + (long)e * Dd + n, flag);
#pragma unroll
    for (int l = 0; l < 7; l++) acc[l] += embsh[l * 768 + e] * wv;
  }
#pragma unroll
  for (int l = 0; l < 7; l++) psum[sub][l][nl] = acc[l];
  __syncthreads();
  if (sub == 0) {
    float bv = ldg_any(bq, z * Dd + n, flag);
#pragma unroll
    for (int l = 0; l < 7; l++) {
      float v = psum[0][l][nl] + psum[1][l][nl] + psum[2][l][nl] + psum[3][l][nl] + bv;
      Qsmall[((long)z * 7 + l) * Dd + n] = fmaxf(v, 0.f);
    }
  }
}

// ---------- emb rows -> outsm[640+l] (bf16) + qmask7 ----------
__global__ __launch_bounds__(256) void emb_copy_kernel(
    const void* __restrict__ emb, bf16* __restrict__ outsm,
    float* __restrict__ qmask7, const int* __restrict__ flags)
{
  int flag = flags[0];
  int l = blockIdx.x;
  int t = threadIdx.x;
  float s = 0.f;
#pragma unroll
  for (int i = 0; i < 3; i++) {
    int e = t + i * 256;
    float v = ldg_any(emb, (long)l * Dd + e, flag);
    outsm[(long)(640 + l) * Dd + e] = __float2bfloat16(v);
    s += v;
  }
  for (int o = 32; o > 0; o >>= 1) s += __shfl_down(s, o);
  __shared__ float red[4];
  if ((t & 63) == 0) red[t >> 6] = s;
  __syncthreads();
  if (t == 0) {
    float tot = red[0] + red[1] + red[2] + red[3];
    qmask7[l] = (tot != 0.f) ? 1.f : 0.f;
  }
}

// ---------- transpose Wk/Wv branch slices to [N][K] bf16 ----------
__global__ __launch_bounds__(256) void transpose2_kernel(
    const void* __restrict__ Wk, const void* __restrict__ Wv,
    bf16* __restrict__ WT, const int* __restrict__ flags)
{
  int flag = flags[0];
  __shared__ float tile[32][33];
  int z = blockIdx.z;
  int m = z >> 1, wsel = z & 1;
  const void* src = wsel ? Wv : Wk;
  long off = (long)m * WSLICE;
  bf16* dst = WT + (long)z * WSLICE;
  int kk0 = blockIdx.y * 32, n0 = blockIdx.x * 32;
  int tx = threadIdx.x & 31, ty = threadIdx.x >> 5;
#pragma unroll
  for (int i = 0; i < 4; i++)
    tile[ty + i * 8][tx] = ldg_any(src, off + (long)(kk0 + ty + i * 8) * Dd + n0 + tx, flag);
  __syncthreads();
#pragma unroll
  for (int i = 0; i < 4; i++)
    dst[(long)(n0 + ty + i * 8) * Dd + kk0 + tx] = __float2bfloat16(tile[tx][ty + i * 8]);
}

// ---------- MFMA GEMM core: C = epi(scale*A@B^T) ----------
// cMode: 0=bf16, 2=fp32, 3=fp16, 5=fp16 transposed via LDS bounce (coalesced).
// cMode 5 REQUIRES As,Bs to be one contiguous 16KB block.
__device__ __forceinline__ void gemm_mfma_core(
    const bf16* __restrict__ Ab, long ldA,
    const bf16* __restrict__ Bbp, long ldB,
    bf16* As, bf16* Bs, int bm, int bn, int K,
    const void* bias, long bOff,
    void* C, long ldC, int cMode,
    float scale, int relu, int fflag)
{
  int tid = threadIdx.x;
  int lane = tid & 63, w = tid >> 6;
  int mo = (w & 1) * 64, no = (w >> 1) * 64;
  int l15 = lane & 15, q4 = lane >> 4;
  int gr = lane >> 2;
  int gs = (lane & 3) * 8;
  const bf16* aS0 = Ab + (long)(bm + w * 16 + gr) * ldA + gs;
  const bf16* aS1 = aS0 + 64 * ldA;
  const bf16* bS0 = Bbp + (long)(bn + w * 16 + gr) * ldB + gs;
  const bf16* bS1 = bS0 + 64 * ldB;
  bf16* aD0 = As + w * 512;
  bf16* aD1 = As + 2048 + w * 512;
  bf16* bD0 = Bs + w * 512;
  bf16* bD1 = Bs + 2048 + w * 512;

  f32x4 acc[4][4];
#pragma unroll
  for (int i = 0; i < 4; i++)
#pragma unroll
    for (int j = 0; j < 4; j++)
#pragma unroll
      for (int r = 0; r < 4; r++) acc[i][j][r] = 0.f;

  for (int k0 = 0; k0 < K; k0 += 32) {
    load_lds16(aS0, aD0);
    load_lds16(aS1, aD1);
    load_lds16(bS0, bD0);
    load_lds16(bS1, bD1);
    aS0 += 32; aS1 += 32; bS0 += 32; bS1 += 32;
    __syncthreads();
    short8 af[4], bfv[4];
#pragma unroll
    for (int i = 0; i < 4; i++)
      af[i] = *(const short8*)(As + (mo + i * 16 + l15) * 32 + q4 * 8);
#pragma unroll
    for (int j = 0; j < 4; j++)
      bfv[j] = *(const short8*)(Bs + (no + j * 16 + l15) * 32 + q4 * 8);
#pragma unroll
    for (int i = 0; i < 4; i++)
#pragma unroll
      for (int j = 0; j < 4; j++)
        acc[i][j] = __builtin_amdgcn_mfma_f32_16x16x32_bf16(af[i], bfv[j], acc[i][j], 0, 0, 0);
    __syncthreads();
  }

  float bsv[4];
#pragma unroll
  for (int j = 0; j < 4; j++) {
    int colg = bn + no + j * 16 + l15;
    bsv[j] = bias ? ldg_any(bias, bOff + colg, fflag) : 0.f;
  }

  if (cMode == 5) {
    unsigned short* tile = (unsigned short*)As;   // [32][136]
    int cl = (no >> 6) * 16 + l15;
#pragma unroll
    for (int j = 0; j < 4; j++) {
      __syncthreads();
#pragma unroll
      for (int i = 0; i < 4; i++) {
#pragma unroll
        for (int r = 0; r < 4; r++) {
          float v = acc[i][j][r] * scale + bsv[j];
          if (relu) v = fmaxf(v, 0.f);
          tile[cl * 136 + mo + i * 16 + q4 * 4 + r] = f2h(v);
        }
      }
      __syncthreads();
#pragma unroll
      for (int uu = 0; uu < 2; uu++) {
        int u = tid + uu * 256;
        int c = u >> 4, mseg = u & 15;
        int colg = bn + (c >> 4) * 64 + j * 16 + (c & 15);
        uint2 v0 = *(const uint2*)(tile + c * 136 + mseg * 8);
        uint2 v1 = *(const uint2*)(tile + c * 136 + mseg * 8 + 4);
        uint4 pk; pk.x = v0.x; pk.y = v0.y; pk.z = v1.x; pk.w = v1.y;
        *(uint4*)((unsigned short*)C + (long)colg * ldC + bm + mseg * 8) = pk;
      }
    }
    return;
  }

#pragma unroll
  for (int i = 0; i < 4; i++) {
#pragma unroll
    for (int j = 0; j < 4; j++) {
      int colg = bn + no + j * 16 + l15;
#pragma unroll
      for (int r = 0; r < 4; r++) {
        int rowg = bm + mo + i * 16 + q4 * 4 + r;
        float v = acc[i][j][r] * scale + bsv[j];
        if (relu) v = fmaxf(v, 0.f);
        long off2 = (long)rowg * ldC + colg;
        if (cMode == 2)      ((float*)C)[off2] = v;
        else if (cMode == 3) ((unsigned short*)C)[off2] = f2h(v);
        else                 ((bf16*)C)[off2] = __float2bfloat16(v);
      }
    }
  }
}

// ---------- K/V projections + seqW, z: 0..21 = m*2+{K,V}; 22,23 = seqW dir ----------
__global__ __launch_bounds__(256, 2) void proj_kernel(
    const bf16* __restrict__ seqb, const bf16* __restrict__ WT,
    const void* __restrict__ bk, const void* __restrict__ bv,
    const bf16* __restrict__ WihB, const float* __restrict__ cbias,
    unsigned short* __restrict__ Kb, unsigned short* __restrict__ Vt,
    bf16* __restrict__ seqW, const int* __restrict__ flags)
{
  __shared__ __align__(16) bf16 smem[8192];   // contiguous As+Bs (cMode 5 needs this)
  bf16* As = smem;
  bf16* Bs = smem + 4096;
  int z = blockIdx.z;
  if (z < 22) {
    int m = z >> 1, wsel = z & 1;
    const bf16* B = WT + (long)z * WSLICE;
    if (wsel == 0) {
      gemm_mfma_core(seqb, Dd, B, Dd, As, Bs, blockIdx.y * 128, blockIdx.x * 128, Dd,
                     bk, (long)m * Dd, Kb + (long)m * 4096 * Dd, Dd, 3, 1.f, 1, flags[0]);
    } else {
      gemm_mfma_core(seqb, Dd, B, Dd, As, Bs, blockIdx.y * 128, blockIdx.x * 128, Dd,
                     bv, (long)m * Dd, Vt + (long)m * Dd * 4096, 4096, 5, 1.f, 1, flags[0]);
    }
  } else {
    int dir = z - 22;
    // bias = bih + bhh(r,z) precomputed in f32 (fflag=1)
    gemm_mfma_core(seqb, Dd, WihB + (long)dir * WSLICE, Dd, As, Bs,
                   blockIdx.y * 128, blockIdx.x * 128, Dd,
                   cbias, (long)dir * Dd, seqW + (long)dir * 4096 * Dd, Dd, 0,
                   1.f, 0, 1);
  }
}

// ---------- PVW = outsm(768 rows incl emb @640) @ Wih^T (fp32), z = dir ----------
__global__ __launch_bounds__(256, 2) void pvw_kernel(
    const bf16* __restrict__ outsm, const bf16* __restrict__ WihB,
    float* __restrict__ PVW, const int* __restrict__ flags)
{
  __shared__ __align__(16) bf16 As[4096];
  __shared__ __align__(16) bf16 Bs[4096];
  int dir = blockIdx.z;
  gemm_mfma_core(outsm, Dd, WihB + (long)dir * WSLICE, Dd, As, Bs,
                 blockIdx.y * 128, blockIdx.x * 128, Dd,
                 nullptr, 0, PVW + (long)dir * 768 * Dd, Dd, 2, 1.f, 0, flags[0]);
}

// ---------- fused scores+softmax+mask+PV per (k,b) ----------
__global__ __launch_bounds__(512, 2) void attn_kernel(
    const unsigned short* __restrict__ Kb, const unsigned short* __restrict__ Vt,
    const float* __restrict__ Qsmall, const float* __restrict__ qmask7,
    bf16* __restrict__ outsm, float scl)
{
  int blk = blockIdx.x;  // k*8+b
  int k = blk >> 3, b = blk & 7;
  int tid = threadIdx.x;
  int lane = tid & 63, w = tid >> 6;
  __shared__ unsigned qs[7][384];
  __shared__ unsigned short ash[7][512];
  __shared__ float wred[8][7];
  __shared__ float gred[7];
  __shared__ float finv[7];
  for (int i = tid; i < 7 * 384; i += 512) {
    int l = i / 384, e2 = i - l * 384;
    const float* qp = Qsmall + ((long)k * 7 + l) * Dd + 2 * e2;
    qs[l][e2] = packh2(qp[0], qp[1]);
  }
  __syncthreads();
  const uint4* Krow = (const uint4*)(Kb + ((long)k * 4096 + b * 512 + tid) * Dd);
  float sc[7] = {};
  for (int e8 = 0; e8 < 96; e8++) {
    uint4 kv = Krow[e8];
#pragma unroll
    for (int l = 0; l < 7; l++) {
      sc[l] = dot2u(qs[l][e8 * 4],     kv.x, sc[l]);
      sc[l] = dot2u(qs[l][e8 * 4 + 1], kv.y, sc[l]);
      sc[l] = dot2u(qs[l][e8 * 4 + 2], kv.z, sc[l]);
      sc[l] = dot2u(qs[l][e8 * 4 + 3], kv.w, sc[l]);
    }
  }
#pragma unroll
  for (int l = 0; l < 7; l++) sc[l] *= scl;
#pragma unroll
  for (int l = 0; l < 7; l++) {
    float v = sc[l];
    for (int o = 32; o > 0; o >>= 1) v = fmaxf(v, __shfl_down(v, o));
    if (lane == 0) wred[w][l] = v;
  }
  __syncthreads();
  if (tid < 7) {
    float m = wred[0][tid];
#pragma unroll
    for (int i = 1; i < 8; i++) m = fmaxf(m, wred[i][tid]);
    gred[tid] = m;
  }
  __syncthreads();
  float ev[7];
#pragma unroll
  for (int l = 0; l < 7; l++) {
    ev[l] = __expf(sc[l] - gred[l]);
    float v = ev[l];
    for (int o = 32; o > 0; o >>= 1) v += __shfl_down(v, o);
    if (lane == 0) wred[w][l] = v;
  }
  __syncthreads();
  if (tid < 7) {
    float s = 0.f;
#pragma unroll
    for (int i = 0; i < 8; i++) s += wred[i][tid];
    finv[tid] = qmask7[tid] / s;
  }
  __syncthreads();
#pragma unroll
  for (int l = 0; l < 7; l++) ash[l][tid] = f2h(ev[l] * finv[l]);
  __syncthreads();
  for (int rep = 0; rep < 2; rep++) {
    int n = tid + rep * 512;
    if (n >= Dd) break;
    const uint4* Vrow = (const uint4*)(Vt + ((long)k * Dd + n) * 4096 + b * 512);
    float acc[7] = {};
    for (int m8 = 0; m8 < 64; m8++) {
      uint4 vv = Vrow[m8];
#pragma unroll
      for (int l = 0; l < 7; l++) {
        const unsigned* ap = (const unsigned*)&ash[l][0];
        acc[l] = dot2u(ap[m8 * 4],     vv.x, acc[l]);
        acc[l] = dot2u(ap[m8 * 4 + 1], vv.y, acc[l]);
        acc[l] = dot2u(ap[m8 * 4 + 2], vv.z, acc[l]);
        acc[l] = dot2u(ap[m8 * 4 + 3], vv.w, acc[l]);
      }
    }
#pragma unroll
    for (int l = 0; l < 7; l++)
      outsm[((long)blk * 7 + l) * Dd + n] = __float2bfloat16(acc[l]);
  }
}

// ---------- GRU v15: fp8 weight cache — fits the 256-reg cap with slack ----
// v14 post-mortem: demand = 192 AGPR (fp16 afr) + ~65 arch = 257, ONE reg
// over the 2-waves/SIMD unified cap of 256 -> allocator spilled (WRITE 45MB).
// v15 halves the weight cache: Whh quantized to OCP e4m3 fp8 (scale x16 to
// avoid subnormals), v_mfma_f32_16x16x32_fp8_fp8 (same shape/rate as f16,
// 2-reg A/B operands). h quantized to fp8 (x16) for the B operand only;
// gate-state h stays f32; matvec output descaled by 1/256. New demand:
// 96 AGPR + 24 acc + 2 bfr + ~40 arch ~= 162 << 256. Hazard scheme = v14
// (proven): one asm block per kt with leading s_nop 1; trailing 3x s_nop 7.
__global__ __launch_bounds__(512) void gru_kernel(
    const bf16* __restrict__ seqW,   // [2][4096][768] bf16, includes bih + bhh(r,z)
    const float* __restrict__ PVW,   // [2][768][768]; rows n*7+l and 640+l(emb)
    const void* __restrict__ labels,
    const void* __restrict__ Whh, const void* __restrict__ bhh,
    float* __restrict__ hbuf, const int* __restrict__ flags)
{
  int flag = flags[0], lflag = flags[1];
  int idx = blockIdx.x;
  int dir = idx / 88, n = idx - dir * 88;
  int b = n & 7;
  int tid = threadIdx.x;
  int lane = tid & 63, w = tid >> 6;
  int l15 = lane & 15, g4 = lane >> 4;

  // A-fragments (fp8): tile t6 (gate g=t6>>1, half hb=t6&1), rows m0..m0+15,
  // m0 = g*256 + 32w + 16*hb. Lane holds 8 consecutive fp8 of
  // W[m0+l15][32kt + 8*g4 + j] (x16 scale). 2 regs/frag, AGPR via "a".
  u32x2 afr[6][8];
#pragma unroll
  for (int t = 0; t < 6; t++) {
    int m0 = (t >> 1) * 256 + 32 * w + (t & 1) * 16;
    long rb = ((long)dir * Dd + m0 + l15) * (long)Hh + 8 * g4;
#pragma unroll
    for (int kt = 0; kt < 8; kt++) {
      long eb = rb + 32 * kt;
      u32x2 u;
      if (flag) {
        const float4* s4 = (const float4*)((const float*)Whh + eb);
        float4 v0 = s4[0], v1 = s4[1];
        u[0] = cvt4_fp8(16.f * v0.x, 16.f * v0.y, 16.f * v0.z, 16.f * v0.w);
        u[1] = cvt4_fp8(16.f * v1.x, 16.f * v1.y, 16.f * v1.z, 16.f * v1.w);
      } else {
        uint4 v = *(const uint4*)((const bf16*)Whh + eb);
        u[0] = cvt4_fp8(16.f * blo(v.x), 16.f * bhi(v.x),
                        16.f * blo(v.y), 16.f * bhi(v.y));
        u[1] = cvt4_fp8(16.f * blo(v.z), 16.f * bhi(v.z),
                        16.f * blo(v.w), 16.f * bhi(v.w));
      }
      afr[t][kt] = u;
    }
  }

  __shared__ float rowsh[7 * 768];
  __shared__ int labsh[512];
  __shared__ __align__(16) float out_lds[768];
  __shared__ __align__(8) unsigned char hsh[256];          // fp8 h (x16)
  __shared__ __align__(16) unsigned short xring[4 * 768];  // 4-deep x-row ring

  for (int i = tid; i < 7 * 768; i += 512) {
    int l = i / 768, row = i - l * 768;
    rowsh[i] = PVW[((long)dir * 768 + n * 7 + l) * Dd + row]
             + PVW[((long)dir * 768 + 640 + l) * Dd + row];
  }
  labsh[tid] = lflag ? (int)((const long long*)labels)[b * 512 + tid]
                     : ((const int*)labels)[b * 512 + tid];
  if (tid < 256) hsh[tid] = 0;   // fp8 zero

  int ch = tid & 255;
  float bh2 = 0.f, hprev = 0.f;
  if (tid < 256) bh2 = ldg_any(bhh, dir * Dd + 512 + ch, flag);

  // x-row DMA: row t is 1536 B; wave0 lanes 0-63 cover bytes 0..1023,
  // wave1 lanes 0-31 cover 1024..1535 (LDS dst = uniform base + lane*16).
  const char* swb = (const char*)seqW + ((long)dir * 4096 + b * 512) * (long)(Dd * 2);
  int dma = (w == 0) || (w == 1 && lane < 32);
  // prime ring slots 0..2
  if (dma) {
#pragma unroll
    for (int s = 0; s < 3; s++) {
      int tp = dir ? 511 - s : s;
      load_lds16(swb + (long)tp * 1536 + w * 1024 + lane * 16,
                 (char*)xring + s * 1536 + w * 1024);
    }
  }
  __syncthreads();   // drains vmcnt(0)+lgkmcnt(0): ring 0..2 ready, hsh ready

  for (int tt = 0; tt < Ss; tt++) {
    // issue DMA for step tt+3 (slot (tt+3)&3); clamped row at the tail
    {
      int ttp = (tt + 3 < Ss) ? tt + 3 : Ss - 1;
      int tp = dir ? 511 - ttp : ttp;
      if (dma)
        load_lds16(swb + (long)tp * 1536 + w * 1024 + lane * 16,
                   (char*)xring + ((tt + 3) & 3) * 1536 + w * 1024);
    }
    // ---- phase A (all 8 waves): out = Whh · h via fp8 asm MFMA ----
    f32x4 a0 = {0.f, 0.f, 0.f, 0.f};
    f32x4 a1 = {0.f, 0.f, 0.f, 0.f};
    f32x4 a2 = {0.f, 0.f, 0.f, 0.f};
    f32x4 a3 = {0.f, 0.f, 0.f, 0.f};
    f32x4 a4 = {0.f, 0.f, 0.f, 0.f};
    f32x4 a5 = {0.f, 0.f, 0.f, 0.f};
#pragma unroll
    for (int kt = 0; kt < 8; kt++) {
      u32x2 bfr = ((const u32x2*)hsh)[4 * kt + g4];   // 8 fp8 of h, broadcast
      // one asm block per kt: leading s_nop 1 guards compiler VALU writes
      // (acc-init movs, tuple copies) against MFMA SrcA/B/C reads.
      asm volatile(
          "s_nop 1\n\t"
          "v_mfma_f32_16x16x32_fp8_fp8 %0, %6, %12, %0\n\t"
          "v_mfma_f32_16x16x32_fp8_fp8 %1, %7, %12, %1\n\t"
          "v_mfma_f32_16x16x32_fp8_fp8 %2, %8, %12, %2\n\t"
          "v_mfma_f32_16x16x32_fp8_fp8 %3, %9, %12, %3\n\t"
          "v_mfma_f32_16x16x32_fp8_fp8 %4, %10, %12, %4\n\t"
          "v_mfma_f32_16x16x32_fp8_fp8 %5, %11, %12, %5"
          : "+v"(a0), "+v"(a1), "+v"(a2), "+v"(a3), "+v"(a4), "+v"(a5)
          : "a"(afr[0][kt]), "a"(afr[1][kt]), "a"(afr[2][kt]),
            "a"(afr[3][kt]), "a"(afr[4][kt]), "a"(afr[5][kt]),
            "v"(bfr));
    }
    // MFMA D write -> VALU/LDS read of acc: generous 24-cycle guard
    asm volatile("s_nop 7\n\ts_nop 7\n\ts_nop 7"
        : "+v"(a0), "+v"(a1), "+v"(a2), "+v"(a3), "+v"(a4), "+v"(a5));
    if (l15 == 0) {   // col-0 lanes hold D[4*g4+r][0] = out[m0+4*g4+r]
      int mb = 32 * w + 4 * g4;
      *(f32x4*)(out_lds + mb)            = a0;   // t6=0: g0, hb0
      *(f32x4*)(out_lds + mb + 16)       = a1;   // t6=1: g0, hb1
      *(f32x4*)(out_lds + 256 + mb)      = a2;   // t6=2: g1, hb0
      *(f32x4*)(out_lds + 256 + mb + 16) = a3;   // t6=3: g1, hb1
      *(f32x4*)(out_lds + 512 + mb)      = a4;   // t6=4: g2, hb0
      *(f32x4*)(out_lds + 512 + mb + 16) = a5;   // t6=5: g2, hb1
    }
    // staging waves: ensure slot tt&3 has landed (3 newest may be in flight)
    if (w < 2) asm volatile("s_waitcnt vmcnt(3)" ::: "memory");
    lds_barrier();
    // ---- phase B (tid<256): gates ----
    if (tid < 256) {
      const float ds = 1.f / 256.f;   // descale x16(W) * x16(h)
      int t = dir ? 511 - tt : tt;
      int lab = labsh[t];
      const float* rs = rowsh + lab * 768;
      const unsigned short* xr16 = xring + (tt & 3) * 768;
      float xr = rs[ch]       + b2f(xr16[ch]);
      float xz = rs[256 + ch] + b2f(xr16[256 + ch]);
      float xn = rs[512 + ch] + b2f(xr16[512 + ch]);
      float ar = out_lds[ch] * ds;
      float az = out_lds[256 + ch] * ds;
      float an = out_lds[512 + ch] * ds;
      float rg = 1.f / (1.f + __expf(-(xr + ar)));        // bhh_r folded
      float zg = 1.f / (1.f + __expf(-(xz + az)));        // bhh_z folded
      float targ = xn + rg * (an + bh2);
      float e2 = __expf(2.f * targ);
      float ng = 1.f - 2.f / (e2 + 1.f);
      float hnew = (1.f - zg) * ng + zg * hprev;
      hprev = hnew;
      hsh[ch] = f2e4m3(hnew * 16.f);
    }
    lds_barrier();
  }
  if (tid < 256) hbuf[((long)(dir * 88 + n)) * Hh + ch] = hprev;
}

// ---------- final head ----------
__global__ __launch_bounds__(256) void head_kernel(
    const float* __restrict__ hbuf, const void* __restrict__ W1,
    const void* __restrict__ b1, void* __restrict__ out,
    const int* __restrict__ flags)
{
  int flag = flags[0];
  int n = blockIdx.x;
  int c = threadIdx.x;
  float v = hbuf[(long)n * Hh + c] * ldg_any(W1, c, flag)
          + hbuf[(long)(88 + n) * Hh + c] * ldg_any(W1, 256 + c, flag);
  for (int o = 32; o > 0; o >>= 1) v += __shfl_down(v, o);
  __shared__ float red[4];
  if ((c & 63) == 0) red[c >> 6] = v;
  __syncthreads();
  if (c == 0) {
    float s = red[0] + red[1] + red[2] + red[3] + ldg_any(b1, 0, flag);
    float sig = 1.f / (1.f + __expf(-s));
    int k = n / Bb, b = n - k * Bb;
    int o = b * NATT + k;
    if (flag) ((float*)out)[o] = sig;
    else      stf((bf16*)out + o, sig);
  }
}

extern "C" void kernel_launch(void* const* d_in, const int* in_sizes, int n_in,
                              void* d_out, int out_size, void* d_ws, size_t ws_size,
                              hipStream_t stream) {
  const void* labels = d_in[0];
  const void* seq  = d_in[1];
  const void* emb  = d_in[2];
  const void* Wq   = d_in[3];
  const void* bq   = d_in[4];
  const void* Wk   = d_in[5];
  const void* bk   = d_in[6];
  const void* Wv   = d_in[7];
  const void* bv   = d_in[8];
  const void* Wih  = d_in[9];
  const void* Whh  = d_in[10];
  const void* bih  = d_in[11];
  const void* bhh  = d_in[12];
  const void* W1   = d_in[13];
  const void* b1   = d_in[14];

  char* p = (char*)d_ws;
  size_t off = 0;
  auto alloc = [&](size_t bytes) -> void* {
    void* r = p + off; off += (bytes + 255) & ~(size_t)255; return r;
  };
  int*    flags  = (int*)alloc(2 * sizeof(int));
  bf16*   seqb   = (bf16*)alloc(4096UL * 768 * 2);
  float*  qmask7 = (float*)alloc(7 * 4);
  float*  Qsmall = (float*)alloc(11UL * 7 * 768 * 4);
  bf16*   WihB   = (bf16*)alloc(2UL * WSLICE * 2);
  bf16*   WT     = (bf16*)alloc(22UL * WSLICE * 2);
  unsigned short* Kb = (unsigned short*)alloc(11UL * 4096 * 768 * 2);
  unsigned short* Vt = (unsigned short*)alloc(11UL * 768 * 4096 * 2);
  bf16*   outsm  = (bf16*)alloc(768UL * 768 * 2);
  float*  PVW    = (float*)alloc(2UL * 768 * 768 * 4);
  bf16*   seqW   = (bf16*)alloc(2UL * 4096 * 768 * 2);
  float*  hbuf   = (float*)alloc(2UL * 88 * 256 * 4);
  float*  cbias  = (float*)alloc(2UL * 768 * 4);
  if (off > ws_size) return;

  probe_kernel<<<1, 64, 0, stream>>>((const unsigned short*)seq,
                                     (const unsigned*)labels, flags);
  conv_seq_kernel<<<4096, 256, 0, stream>>>(seq, seqb, flags);
  convert_kernel<<<(int)((2 * WSLICE + 255) / 256), 256, 0, stream>>>(
      Wih, WihB, 2L * WSLICE, flags);
  cbias_kernel<<<6, 256, 0, stream>>>(bih, bhh, cbias, flags);
  smalls_kernel<<<dim3(12, 11), 256, 0, stream>>>(emb, Wq, bq, Qsmall, flags);
  emb_copy_kernel<<<7, 256, 0, stream>>>(emb, outsm, qmask7, flags);
  transpose2_kernel<<<dim3(24, 24, 22), 256, 0, stream>>>(Wk, Wv, WT, flags);
  proj_kernel<<<dim3(6, 32, 24), 256, 0, stream>>>(
      seqb, WT, bk, bv, WihB, cbias, Kb, Vt, seqW, flags);
  const float scl = 1.f / sqrtf(768.f);
  attn_kernel<<<88, 512, 0, stream>>>(Kb, Vt, Qsmall, qmask7, outsm, scl);
  pvw_kernel<<<dim3(6, 6, 2), 256, 0, stream>>>(outsm, WihB, PVW, flags);
  gru_kernel<<<176, 512, 0, stream>>>(seqW, PVW, labels, Whh, bhh, hbuf, flags);
  head_kernel<<<88, 256, 0, stream>>>(hbuf, W1, b1, d_out, flags);
}